// Round 1
// baseline (22340.292 us; speedup 1.0000x reference)
//
#include <hip/hip_runtime.h>
#include <math.h>
#include <stdint.h>

#define CTX 77
#define WIDTH 512
#define HEADS 8
#define DH 64
#define LAYERS 12
#define EMBED 1024
#define NTXT 128
#define PP 8
#define LPROMPT 16
#define EOTTOK 49407
#define BSEQ (PP*NTXT)          // 1024
#define ROWS (BSEQ*CTX)         // 78848

typedef unsigned short ushort_t;
typedef __attribute__((ext_vector_type(8))) short short8;
typedef __attribute__((ext_vector_type(4))) float floatx4;

__device__ __forceinline__ float b2f(ushort_t u){
  union { unsigned int i; float f; } x; x.i = ((unsigned int)u) << 16; return x.f;
}
__device__ __forceinline__ ushort_t f2b(float f){
  union { float f; unsigned int i; } x; x.f = f;
  unsigned int r = x.i + 0x7fffu + ((x.i >> 16) & 1u);
  return (ushort_t)(r >> 16);
}
__device__ __forceinline__ float wsum(float v){
  #pragma unroll
  for (int o = 32; o > 0; o >>= 1) v += __shfl_xor(v, o, 64);
  return v;
}
__device__ __forceinline__ float wmax(float v){
  #pragma unroll
  for (int o = 32; o > 0; o >>= 1) v = fmaxf(v, __shfl_xor(v, o, 64));
  return v;
}

// async global->LDS, 16 B per lane; LDS dest = wave-uniform base + lane*16.
__device__ __forceinline__ void async16(const void* g, void* l){
  __builtin_amdgcn_global_load_lds(
      (const __attribute__((address_space(1))) void*)(uintptr_t)g,
      (__attribute__((address_space(3))) void*)(uint32_t)(uintptr_t)l,
      16, 0, 0);
}

// -------- fp32 -> bf16 weight conversion (RNE), 4 elems/thread --------
__global__ __launch_bounds__(256) void k_conv(
    const float* __restrict__ s, ushort_t* __restrict__ d, int n4)
{
  int i = blockIdx.x * 256 + threadIdx.x;
  if (i < n4){
    float4 v = ((const float4*)s)[i];
    ushort_t o[4] = { f2b(v.x), f2b(v.y), f2b(v.z), f2b(v.w) };
    ((int2*)d)[i] = *(int2*)o;
  }
}

// -------- pos_y: first EOT position per text row --------
__global__ void k_posy(const int* __restrict__ text, int* __restrict__ posy){
  int n = threadIdx.x;
  if (n < NTXT){
    int p = 0;
    for (int t = 0; t < CTX; ++t){ if (text[n*CTX + t] == EOTTOK){ p = t; break; } }
    posy[n] = p;
  }
}

// -------- embedding + prompt splice + pos_emb -> H --------
template<bool RF32>
__global__ __launch_bounds__(256) void k_embed(
    const int* __restrict__ text, const float* __restrict__ cprompt,
    const float* __restrict__ tok_emb, const float* __restrict__ pos_emb,
    const int* __restrict__ posy, void* __restrict__ Hp)
{
  long long idx = (long long)blockIdx.x * 256 + threadIdx.x;
  int d   = (int)(idx & 511);
  int row = (int)(idx >> 9);
  int t  = row % CTX;
  int pn = row / CTX;
  int n  = pn % NTXT;
  int p  = pn / NTXT;
  int py = posy[n];
  float v;
  if (t >= py && t < py + LPROMPT){
    int pidx = t - py;
    v = cprompt[(p*LPROMPT + pidx)*WIDTH + d];
  } else {
    int src = (t < py) ? t : (t - LPROMPT + 1);
    src = min(max(src, 0), CTX-1);
    int tok = text[n*CTX + src];
    v = tok_emb[(long long)tok*WIDTH + d];
  }
  v += pos_emb[t*WIDTH + d];
  if constexpr (RF32) ((float*)Hp)[idx] = v;
  else                ((ushort_t*)Hp)[idx] = f2b(v);
}

// -------- LayerNorm: H -> Y(bf16), one wave per 512-row --------
template<bool RF32>
__global__ __launch_bounds__(256) void k_ln(
    const void* __restrict__ Hp, const float* __restrict__ w,
    const float* __restrict__ b, ushort_t* __restrict__ Y, int nrows)
{
  int wid = threadIdx.x >> 6, lane = threadIdx.x & 63;
  int row = blockIdx.x * 4 + wid;
  if (row >= nrows) return;
  float v[8];
  if constexpr (RF32){
    const float* x = (const float*)Hp + (long long)row * WIDTH;
    #pragma unroll
    for (int i = 0; i < 8; ++i) v[i] = x[lane*8 + i];
  } else {
    const ushort_t* x = (const ushort_t*)Hp + (long long)row * WIDTH;
    int4 raw = *(const int4*)(x + lane*8);
    ushort_t* u = (ushort_t*)&raw;
    #pragma unroll
    for (int i = 0; i < 8; ++i) v[i] = b2f(u[i]);
  }
  float s = 0.f, ss = 0.f;
  #pragma unroll
  for (int i = 0; i < 8; ++i){ s += v[i]; ss += v[i]*v[i]; }
  s = wsum(s); ss = wsum(ss);
  float mean = s * (1.0f/WIDTH);
  float var  = ss * (1.0f/WIDTH) - mean*mean;
  float rs = rsqrtf(var + 1e-5f);
  ushort_t o[8];
  #pragma unroll
  for (int i = 0; i < 8; ++i){
    int d = lane*8 + i;
    o[i] = f2b((v[i]-mean)*rs*w[d] + b[d]);
  }
  *(int4*)(Y + (long long)row*WIDTH + lane*8) = *(int4*)o;
}

// ============================================================================
// GEMM: C[M,N] = A[M,K](bf16) @ W[N,K]^T(bf16) + bias(fp32)
// 256x256 tile, BK=64, 8 waves (2x4), 128 KiB LDS, 8-phase-style schedule:
// per K-tile 4 phases {ds_read frags | stage 2 quarters -> barrier ->
// lgkmcnt(0) -> setprio(1) 16xMFMA setprio(0) -> [counted vmcnt] -> barrier}.
// Counted vmcnt (never 0 in steady state): stage order per K-tile is
// B0,B1 | B2,B3 | A0,A2 | A1,A3  (A1/A3 = qm=1 quarters, needed only at P3),
// so vmcnt(2) at K-tile boundary and vmcnt(4) at mid-tile are exact.
// LDS swizzle: byte ^= ((byte>>7)&7)<<4 within each 8 KiB quarter
// (uniform 8-slot spread -> conflict-free ds_read_b128). global_load_lds
// writes linearly, so the SOURCE global address is pre-swizzled (rule #21).
// MODE 0: O=bf16(acc+bias)  MODE 1: O=bf16(gelu(acc+bias))  MODE 2: H += acc+bias
// M-tail: staging may read past A's end (all A sources have >=1MB of
// workspace after them); MFMA rows are independent; stores guarded by row<M.
// ============================================================================
template<int MODE, bool RF32>
__global__ __launch_bounds__(512) void k_gemm256(
    const ushort_t* __restrict__ A, const ushort_t* __restrict__ W,
    const float* __restrict__ bias, void* __restrict__ Hp,
    ushort_t* __restrict__ O, int K, int N, int M)
{
  __shared__ ushort_t smem[65536];          // 128 KiB: A [0,64K) B [64K,128K)
  char* const sb = (char*)smem;

  const int tid  = threadIdx.x;
  const int lane = tid & 63, wid = tid >> 6;
  const int wm = wid >> 2, wn = wid & 3;    // 2 x 4 wave grid, 128x64 out/wave
  const int quad = lane >> 4, r = lane & 15;

  // T1: XCD-aware bijective block swizzle (m204)
  const int gx   = gridDim.x;
  const int nwg  = gx * gridDim.y;
  const int orig = blockIdx.y * gx + blockIdx.x;
  const int qq = nwg >> 3, rmd = nwg & 7, xcd = orig & 7, loc = orig >> 3;
  const int wg = (xcd < rmd ? xcd * (qq + 1) : rmd * (qq + 1) + (xcd - rmd) * qq) + loc;
  const int n0 = (wg % gx) * 256;
  const long long m0 = (long long)(wg / gx) * 256;

  // staging: thread tid fills LDS bytes [tid*16, tid*16+16) of one 8KiB
  // quarter (64 rows x 64 k). Pre-swizzled source so swizzled reads match.
  const int srow = tid >> 3;                       // logical row in quarter
  const int sc8  = ((tid ^ (tid >> 3)) & 7) * 8;   // swizzled 8-elem k-chunk
  const ushort_t* const pA = A + (m0 + srow) * (long long)K + sc8;
  const ushort_t* const pB = W + ((long long)n0 + srow) * K + sc8;
  const int q64K = K << 6;                         // elems per quarter (64 rows)
  const int ldst = wid << 10;                      // wave-uniform LDS sub-base

  // swizzled read k-offsets (bytes within the 128B row), s = 0/1
  const int k00 = (quad * 16) ^ ((r & 7) << 4);
  const int k01 = (64 + quad * 16) ^ ((r & 7) << 4);

  floatx4 acc[8][4];
  #pragma unroll
  for (int i = 0; i < 8; ++i)
    #pragma unroll
    for (int j = 0; j < 4; ++j){ floatx4 z = {0.f,0.f,0.f,0.f}; acc[i][j] = z; }

  short8 af[4][2];       // current qm half, 4 m-frags x 2 ksteps
  short8 bf[2][2][2];    // [qn][j][s], both qn halves stay live

  // ---- prologue: stage K-tile 0 into buf0 (order fixes vmcnt counts) ----
  async16(pB,            sb + 65536 + 0*8192 + ldst);
  async16(pB +   q64K,   sb + 65536 + 1*8192 + ldst);
  async16(pB + 2*q64K,   sb + 65536 + 2*8192 + ldst);
  async16(pB + 3*q64K,   sb + 65536 + 3*8192 + ldst);
  async16(pA,            sb + 0*8192 + ldst);
  async16(pA + 2*q64K,   sb + 2*8192 + ldst);
  async16(pA +   q64K,   sb + 1*8192 + ldst);
  async16(pA + 3*q64K,   sb + 3*8192 + ldst);
  asm volatile("s_waitcnt vmcnt(2)" ::: "memory");   // B0-3 + A(qm0) landed
  __builtin_amdgcn_s_barrier();
  __builtin_amdgcn_sched_barrier(0);

  const int NK    = K >> 6;
  const int abase = wm * 2 * 8192;      // this wave's A quarter (qm=0)
  const int bbase = 65536 + wn * 8192;  // this wave's B quarter

  for (int kt = 0; kt < NK; ++kt){
    const int cb = (kt & 1) << 15;      // current buf byte offset
    const int nb = cb ^ 32768;          // next buf
    const int ko = (kt + 1) << 6;       // next K-tile elem offset
    const bool st = (kt + 1 < NK);      // block-uniform

    // ---------------- P1: quadrant (qm0,qn0) ----------------
    {
      char* qa = sb + cb + abase;
      #pragma unroll
      for (int i = 0; i < 4; ++i){
        af[i][0] = *(const short8*)(qa + (i*16 + r)*128 + k00);
        af[i][1] = *(const short8*)(qa + (i*16 + r)*128 + k01);
      }
      char* qb = sb + cb + bbase;
      #pragma unroll
      for (int j = 0; j < 2; ++j){
        bf[0][j][0] = *(const short8*)(qb + (j*16 + r)*128 + k00);
        bf[0][j][1] = *(const short8*)(qb + (j*16 + r)*128 + k01);
      }
    }
    if (st){
      async16(pB + ko,        sb + nb + 65536 + 0*8192 + ldst);
      async16(pB + ko + q64K, sb + nb + 65536 + 1*8192 + ldst);
    }
    __builtin_amdgcn_s_barrier();
    asm volatile("s_waitcnt lgkmcnt(0)" ::: "memory");
    __builtin_amdgcn_sched_barrier(0);
    __builtin_amdgcn_s_setprio(1);
    #pragma unroll
    for (int s = 0; s < 2; ++s)
      #pragma unroll
      for (int i = 0; i < 4; ++i)
        #pragma unroll
        for (int j = 0; j < 2; ++j)
          acc[i][j] = __builtin_amdgcn_mfma_f32_16x16x32_bf16(af[i][s], bf[0][j][s], acc[i][j], 0,0,0);
    __builtin_amdgcn_s_setprio(0);
    __builtin_amdgcn_s_barrier();

    // ---------------- P2: quadrant (qm0,qn1) ----------------
    {
      char* qb = sb + cb + bbase;
      #pragma unroll
      for (int j = 0; j < 2; ++j){
        bf[1][j][0] = *(const short8*)(qb + (32 + j*16 + r)*128 + k00);
        bf[1][j][1] = *(const short8*)(qb + (32 + j*16 + r)*128 + k01);
      }
    }
    if (st){
      async16(pB + ko + 2*q64K, sb + nb + 65536 + 2*8192 + ldst);
      async16(pB + ko + 3*q64K, sb + nb + 65536 + 3*8192 + ldst);
    }
    __builtin_amdgcn_s_barrier();
    asm volatile("s_waitcnt lgkmcnt(0)" ::: "memory");
    __builtin_amdgcn_sched_barrier(0);
    __builtin_amdgcn_s_setprio(1);
    #pragma unroll
    for (int s = 0; s < 2; ++s)
      #pragma unroll
      for (int i = 0; i < 4; ++i)
        #pragma unroll
        for (int j = 0; j < 2; ++j)
          acc[i][2+j] = __builtin_amdgcn_mfma_f32_16x16x32_bf16(af[i][s], bf[1][j][s], acc[i][2+j], 0,0,0);
    __builtin_amdgcn_s_setprio(0);
    // mid-tile wait: this tile's A(qm1) quarters must be landed for P3.
    if (st) asm volatile("s_waitcnt vmcnt(4)" ::: "memory");
    else    asm volatile("s_waitcnt vmcnt(0)" ::: "memory");
    __builtin_amdgcn_s_barrier();

    // ---------------- P3: quadrant (qm1,qn1) ----------------
    {
      char* qa = sb + cb + abase + 8192;
      #pragma unroll
      for (int i = 0; i < 4; ++i){
        af[i][0] = *(const short8*)(qa + (i*16 + r)*128 + k00);
        af[i][1] = *(const short8*)(qa + (i*16 + r)*128 + k01);
      }
    }
    if (st){
      async16(pA + ko,          sb + nb + 0*8192 + ldst);
      async16(pA + ko + 2*q64K, sb + nb + 2*8192 + ldst);
    }
    __builtin_amdgcn_s_barrier();
    asm volatile("s_waitcnt lgkmcnt(0)" ::: "memory");
    __builtin_amdgcn_sched_barrier(0);
    __builtin_amdgcn_s_setprio(1);
    #pragma unroll
    for (int s = 0; s < 2; ++s)
      #pragma unroll
      for (int i = 0; i < 4; ++i)
        #pragma unroll
        for (int j = 0; j < 2; ++j)
          acc[4+i][2+j] = __builtin_amdgcn_mfma_f32_16x16x32_bf16(af[i][s], bf[1][j][s], acc[4+i][2+j], 0,0,0);
    __builtin_amdgcn_s_setprio(0);
    __builtin_amdgcn_s_barrier();

    // ---------------- P4: quadrant (qm1,qn0), frags all in regs ----------------
    if (st){
      async16(pA + ko +   q64K, sb + nb + 1*8192 + ldst);
      async16(pA + ko + 3*q64K, sb + nb + 3*8192 + ldst);
    }
    __builtin_amdgcn_s_barrier();
    __builtin_amdgcn_s_setprio(1);
    #pragma unroll
    for (int s = 0; s < 2; ++s)
      #pragma unroll
      for (int i = 0; i < 4; ++i)
        #pragma unroll
        for (int j = 0; j < 2; ++j)
          acc[4+i][j] = __builtin_amdgcn_mfma_f32_16x16x32_bf16(af[i][s], bf[0][j][s], acc[4+i][j], 0,0,0);
    __builtin_amdgcn_s_setprio(0);
    // K-tile boundary wait: next tile's B0-3 + A(qm0) landed (A(qm1) may fly)
    if (st) asm volatile("s_waitcnt vmcnt(2)" ::: "memory");
    __builtin_amdgcn_s_barrier();
    __builtin_amdgcn_sched_barrier(0);
  }

  // ---------------- epilogue ----------------
  float bv[4];
  #pragma unroll
  for (int nj = 0; nj < 4; ++nj) bv[nj] = bias[n0 + wn*64 + nj*16 + r];

  #pragma unroll
  for (int mi = 0; mi < 8; ++mi){
    const long long growb = m0 + wm*128 + mi*16 + quad*4;
    #pragma unroll
    for (int nj = 0; nj < 4; ++nj){
      const int gcol = n0 + wn*64 + nj*16 + r;
      #pragma unroll
      for (int rg = 0; rg < 4; ++rg){
        const long long grow = growb + rg;
        if (grow < M){
          float v = acc[mi][nj][rg] + bv[nj];
          long long idx = grow * (long long)N + gcol;
          if (MODE == 0){
            O[idx] = f2b(v);
          } else if (MODE == 1){
            float g = v / (1.0f + __expf(-1.702f*v));
            O[idx] = f2b(g);
          } else {
            if constexpr (RF32) ((float*)Hp)[idx] += v;
            else { ushort_t* hb = (ushort_t*)Hp; hb[idx] = f2b(b2f(hb[idx]) + v); }
          }
        }
      }
    }
  }
}

// -------- MFMA causal attention: one block per (seq b, head h) --------
__global__ __launch_bounds__(256) void k_attn(
    const ushort_t* __restrict__ QKV, ushort_t* __restrict__ Y)
{
  __shared__ char smem[55872];
  ushort_t* Qs = (ushort_t*)smem;
  ushort_t* Ks = (ushort_t*)(smem + 11520);
  float*    Ss = (float*)smem;
  ushort_t* Vt = (ushort_t*)(smem + 25920);
  ushort_t* Ps = (ushort_t*)(smem + 39232);

  int b = blockIdx.x >> 3, h = blockIdx.x & 7;
  int tid = threadIdx.x;
  int lane = tid & 63, wid = tid >> 6;
  int quad = lane >> 4, r = lane & 15;
  const ushort_t* base = QKV + (size_t)b*CTX*1536 + h*64;

  #pragma unroll
  for (int it = 0; it < 5; ++it){
    int id = tid + it*256;            // 0..1279 = 80 rows * 16 chunks
    int t  = id >> 4;
    int d4 = (id & 15) * 4;
    ushort_t q[4], k[4], v[4];
    if (t < CTX){
      const ushort_t* rp = base + (size_t)t*1536 + d4;
      *(int2*)q = *(const int2*)(rp);
      *(int2*)k = *(const int2*)(rp + 512);
      *(int2*)v = *(const int2*)(rp + 1024);
    } else {
      q[0]=q[1]=q[2]=q[3]=0; k[0]=k[1]=k[2]=k[3]=0; v[0]=v[1]=v[2]=v[3]=0;
    }
    *(int2*)(Qs + t*72 + d4) = *(int2*)q;
    *(int2*)(Ks + t*72 + d4) = *(int2*)k;
    #pragma unroll
    for (int i = 0; i < 4; ++i) Vt[(d4+i)*104 + t] = v[i];
  }
  { // zero Vt key-columns 80..95
    int z = tid * 4;
    int d = z >> 4, c = 80 + (z & 15);
    ushort_t zz[4] = {0,0,0,0};
    *(int2*)(Vt + d*104 + c) = *(int2*)zz;
  }
  __syncthreads();

  const int TI[15] = {0,1,1,2,2,2,3,3,3,3,4,4,4,4,4};
  const int TJ[15] = {0,0,1,0,1,2,0,1,2,3,0,1,2,3,4};
  floatx4 cS[4];
  int ntile = 0;
  for (int tt = wid; tt < 15; tt += 4, ++ntile){
    int i = TI[tt], j = TJ[tt];
    floatx4 c = {0.f,0.f,0.f,0.f};
    #pragma unroll
    for (int s = 0; s < 2; ++s){
      short8 aq = *(const short8*)(Qs + (i*16 + r)*72 + s*32 + quad*8);
      short8 bk = *(const short8*)(Ks + (j*16 + r)*72 + s*32 + quad*8);
      c = __builtin_amdgcn_mfma_f32_16x16x32_bf16(aq, bk, c, 0, 0, 0);
    }
    cS[ntile] = c;
  }
  __syncthreads();

  {
    int idx = 0;
    for (int tt = wid; tt < 15; tt += 4, ++idx){
      int i = TI[tt], j = TJ[tt];
      #pragma unroll
      for (int rg = 0; rg < 4; ++rg){
        int q  = i*16 + quad*4 + rg;
        int kk = j*16 + r;
        float s = cS[idx][rg] * 0.125f;
        if (kk > q) s = -1e30f;
        Ss[q*81 + kk] = s;
      }
    }
  }
  __syncthreads();

  for (int q = wid; q < 80; q += 4){
    if (q >= CTX){
      Ps[q*104 + lane] = 0;
      if (lane < 32) Ps[q*104 + 64 + lane] = 0;
      continue;
    }
    int k1 = 64 + lane;
    float s0 = (lane <= q) ? Ss[q*81 + lane] : -1e30f;
    float s1 = (k1  <= q) ? Ss[q*81 + k1 ]  : -1e30f;
    float mx = wmax(fmaxf(s0, s1));
    float e0 = (lane <= q) ? __expf(s0 - mx) : 0.0f;
    float e1 = (k1  <= q) ? __expf(s1 - mx) : 0.0f;
    float inv = 1.0f / wsum(e0 + e1);
    Ps[q*104 + lane] = f2b(e0 * inv);
    if (lane < 32) Ps[q*104 + 64 + lane] = f2b(e1 * inv);
  }
  __syncthreads();

  for (int tt = wid; tt < 20; tt += 4){
    int mi = tt >> 2, ni = tt & 3;
    floatx4 c = {0.f,0.f,0.f,0.f};
    #pragma unroll
    for (int kc = 0; kc < 3; ++kc){
      short8 ap = *(const short8*)(Ps + (mi*16 + r)*104 + kc*32 + quad*8);
      short8 bv = *(const short8*)(Vt + (ni*16 + r)*104 + kc*32 + quad*8);
      c = __builtin_amdgcn_mfma_f32_16x16x32_bf16(ap, bv, c, 0, 0, 0);
    }
    #pragma unroll
    for (int rg = 0; rg < 4; ++rg){
      int q = mi*16 + quad*4 + rg;
      if (q < CTX)
        Y[((size_t)b*CTX + q)*WIDTH + h*64 + ni*16 + r] = f2b(c[rg]);
    }
  }
}

// -------- gather EOT+LP-1 rows, final LN -> FI (bf16 [1024,512]) --------
template<bool RF32>
__global__ __launch_bounds__(256) void k_lnf_gather(
    const void* __restrict__ Hp, const int* __restrict__ posy,
    const float* __restrict__ w, const float* __restrict__ b,
    ushort_t* __restrict__ FI)
{
  int wid = threadIdx.x >> 6, lane = threadIdx.x & 63;
  int rr = blockIdx.x * 4 + wid;
  if (rr >= BSEQ) return;
  int n = rr % NTXT;
  int tok = posy[n] + LPROMPT - 1;
  long long row = (long long)rr*CTX + tok;
  float v[8];
  if constexpr (RF32){
    const float* x = (const float*)Hp + row * WIDTH;
    #pragma unroll
    for (int i = 0; i < 8; ++i) v[i] = x[lane*8 + i];
  } else {
    const ushort_t* x = (const ushort_t*)Hp + row * WIDTH;
    int4 raw = *(const int4*)(x + lane*8);
    ushort_t* u = (ushort_t*)&raw;
    #pragma unroll
    for (int i = 0; i < 8; ++i) v[i] = b2f(u[i]);
  }
  float s = 0.f, ss = 0.f;
  #pragma unroll
  for (int i = 0; i < 8; ++i){ s += v[i]; ss += v[i]*v[i]; }
  s = wsum(s); ss = wsum(ss);
  float mean = s * (1.0f/WIDTH);
  float var  = ss * (1.0f/WIDTH) - mean*mean;
  float rs = rsqrtf(var + 1e-5f);
  ushort_t o[8];
  #pragma unroll
  for (int i = 0; i < 8; ++i){
    int d = lane*8 + i;
    o[i] = f2b((v[i]-mean)*rs*w[d] + b[d]);
  }
  *(int4*)(FI + (long long)rr*WIDTH + lane*8) = *(int4*)o;
}

// -------- final projection: F[1024,1024] = FI[1024,512](bf16) @ TP[512,1024](fp32) --------
__global__ __launch_bounds__(256) void k_fproj(
    const ushort_t* __restrict__ FI, const float* __restrict__ TP,
    float* __restrict__ F)
{
  int idx = blockIdx.x * 256 + threadIdx.x;
  int e = idx & (EMBED-1);
  int m = idx >> 10;
  float acc = 0.f;
  #pragma unroll 8
  for (int k = 0; k < WIDTH; ++k)
    acc += b2f(FI[m*WIDTH + k]) * TP[k*EMBED + e];
  F[idx] = acc;
}

// -------- per-row L2 normalize in place --------
__global__ __launch_bounds__(256) void k_rownorm(float* __restrict__ F)
{
  __shared__ float red[4];
  int rr = blockIdx.x;
  float* x = F + (long long)rr*EMBED;
  float ss = 0.f;
  for (int i = threadIdx.x; i < EMBED; i += 256){ float v = x[i]; ss += v*v; }
  ss = wsum(ss);
  int wid = threadIdx.x >> 6, lane = threadIdx.x & 63;
  if (lane == 0) red[wid] = ss;
  __syncthreads();
  float inv = rsqrtf(red[0]+red[1]+red[2]+red[3]);
  for (int i = threadIdx.x; i < EMBED; i += 256) x[i] *= inv;
}

// -------- mean over n, normalize, write fp32 out --------
__global__ __launch_bounds__(256) void k_meannorm(
    const float* __restrict__ F, float* __restrict__ OUT)
{
  __shared__ float red[4];
  int p = blockIdx.x;
  float m[4]; float ss = 0.f;
  #pragma unroll
  for (int j = 0; j < 4; ++j){
    int e = threadIdx.x + j*256;
    float s = 0.f;
    for (int n = 0; n < NTXT; ++n) s += F[((long long)(p*NTXT + n))*EMBED + e];
    s *= (1.0f/NTXT);
    m[j] = s; ss += s*s;
  }
  ss = wsum(ss);
  int wid = threadIdx.x >> 6, lane = threadIdx.x & 63;
  if (lane == 0) red[wid] = ss;
  __syncthreads();
  float inv = rsqrtf(red[0]+red[1]+red[2]+red[3]);
  #pragma unroll
  for (int j = 0; j < 4; ++j)
    OUT[p*EMBED + threadIdx.x + j*256] = m[j]*inv;
}

// ============================ launcher ============================

template<bool RF32>
static void run_all(const int* text, const float* cprompt, const float* tok_emb,
                    const float* pos_emb,
                    const ushort_t* Wqkv, const float* qkv_b,
                    const ushort_t* Wout, const float* out_b,
                    const float* ln1_w, const float* ln1_b,
                    const float* ln2_w, const float* ln2_b,
                    const ushort_t* Wfc, const float* fc_b,
                    const ushort_t* Wproj, const float* proj_b,
                    const float* lnf_w, const float* lnf_b, const float* tproj,
                    int* posy, void* H, ushort_t* Y, ushort_t* BIG,
                    ushort_t* FI, float* F, float* OUT, int sc, hipStream_t stream)
{
  const int rows_c = ROWS / sc;
  const int seqs_c = BSEQ / sc;
  const int gy_c   = (rows_c + 255) / 256;
  const int gy_f   = (ROWS + 255) / 256;

  k_posy<<<1, 128, 0, stream>>>(text, posy);
  k_embed<RF32><<<(ROWS*512)/256, 256, 0, stream>>>(text, cprompt, tok_emb, pos_emb, posy, H);

  for (int L = 0; L < LAYERS; ++L){
    k_ln<RF32><<<ROWS/4, 256, 0, stream>>>(H, ln1_w + L*WIDTH, ln1_b + L*WIDTH, Y, ROWS);
    for (int c = 0; c < sc; ++c){
      size_t r0 = (size_t)c * rows_c;
      k_gemm256<0,RF32><<<dim3(6, gy_c), 512, 0, stream>>>(
          Y + r0*WIDTH, Wqkv + (size_t)L*1536*512, qkv_b + L*1536,
          nullptr, BIG, 512, 1536, rows_c);
      k_attn<<<seqs_c*HEADS, 256, 0, stream>>>(BIG, Y + r0*WIDTH);
    }
    k_gemm256<2,RF32><<<dim3(2, gy_f), 512, 0, stream>>>(
        Y, Wout + (size_t)L*512*512, out_b + L*512, H, nullptr, 512, 512, ROWS);
    k_ln<RF32><<<ROWS/4, 256, 0, stream>>>(H, ln2_w + L*WIDTH, ln2_b + L*WIDTH, Y, ROWS);
    for (int c = 0; c < sc; ++c){
      size_t r0 = (size_t)c * rows_c;
      void* Hoff = RF32 ? (void*)((float*)H + r0*WIDTH) : (void*)((ushort_t*)H + r0*WIDTH);
      k_gemm256<1,RF32><<<dim3(8, gy_c), 512, 0, stream>>>(
          Y + r0*WIDTH, Wfc + (size_t)L*2048*512, fc_b + L*2048,
          nullptr, BIG, 512, 2048, rows_c);
      k_gemm256<2,RF32><<<dim3(2, gy_c), 512, 0, stream>>>(
          BIG, Wproj + (size_t)L*512*2048, proj_b + L*512, Hoff, nullptr, 2048, 512, rows_c);
    }
  }

  k_lnf_gather<RF32><<<BSEQ/4, 256, 0, stream>>>(H, posy, lnf_w, lnf_b, FI);
  k_fproj<<<(BSEQ*EMBED)/256, 256, 0, stream>>>(FI, tproj, F);
  k_rownorm<<<BSEQ, 256, 0, stream>>>(F);
  k_meannorm<<<PP, 256, 0, stream>>>(F, OUT);
}

extern "C" void kernel_launch(void* const* d_in, const int* in_sizes, int n_in,
                              void* d_out, int out_size, void* d_ws, size_t ws_size,
                              hipStream_t stream)
{
  const int*   text    = (const int*)d_in[0];
  const float* cprompt = (const float*)d_in[1];
  const float* tok_emb = (const float*)d_in[2];
  const float* pos_emb = (const float*)d_in[3];
  const float* qkv_w   = (const float*)d_in[4];
  const float* qkv_b   = (const float*)d_in[5];
  const float* out_w   = (const float*)d_in[6];
  const float* out_b   = (const float*)d_in[7];
  const float* ln1_w   = (const float*)d_in[8];
  const float* ln1_b   = (const float*)d_in[9];
  const float* ln2_w   = (const float*)d_in[10];
  const float* ln2_b   = (const float*)d_in[11];
  const float* fc_w    = (const float*)d_in[12];
  const float* fc_b    = (const float*)d_in[13];
  const float* proj_w  = (const float*)d_in[14];
  const float* proj_b  = (const float*)d_in[15];
  const float* lnf_w   = (const float*)d_in[16];
  const float* lnf_b   = (const float*)d_in[17];
  const float* tproj   = (const float*)d_in[18];

  const size_t nQKV = (size_t)LAYERS*1536*512;
  const size_t nOUT = (size_t)LAYERS*512*512;
  const size_t nFC  = (size_t)LAYERS*2048*512;
  const size_t nPRJ = (size_t)LAYERS*512*2048;
  const size_t nWB  = nQKV + nOUT + nFC + nPRJ;

  auto al = [](size_t b){ return (b + 255) & ~(size_t)255; };
  const size_t fixed = al(NTXT*sizeof(int)) + al((size_t)ROWS*WIDTH*2 /*Y*/)
                     + al((size_t)BSEQ*WIDTH*2 /*FI*/) + al((size_t)BSEQ*EMBED*4 /*F*/)
                     + al(nWB*2);
  int sc = 8; bool hf32 = false;
  const int scs[4] = {1, 2, 4, 8};
  bool found = false;
  for (int pass = 0; pass < 2 && !found; ++pass){
    size_t hbytes = (size_t)ROWS*WIDTH*(pass == 0 ? 4 : 2);
    for (int i = 0; i < 4; ++i){
      size_t big = (size_t)(ROWS/scs[i]) * 2048 * 2;
      if (fixed + al(hbytes) + al(big) <= ws_size){
        sc = scs[i]; hf32 = (pass == 0); found = true; break;
      }
    }
  }

  char* ws = (char*)d_ws;
  size_t off = 0;
  auto alloc = [&](size_t bytes)->char*{
    char* pp = ws + off; off += (bytes + 255) & ~(size_t)255; return pp;
  };
  int*      posy = (int*)     alloc(NTXT*sizeof(int));
  void*     H    = (void*)    alloc((size_t)ROWS*WIDTH*(hf32 ? 4 : 2));
  ushort_t* Y    = (ushort_t*)alloc((size_t)ROWS*WIDTH*2);
  ushort_t* BIG  = (ushort_t*)alloc((size_t)(ROWS/sc)*2048*2);
  ushort_t* FI   = (ushort_t*)alloc((size_t)BSEQ*WIDTH*2);
  float*    F    = (float*)   alloc((size_t)BSEQ*EMBED*4);
  ushort_t* WB   = (ushort_t*)alloc(nWB*2);
  ushort_t* Wqkv = WB;
  ushort_t* Wout = WB + nQKV;
  ushort_t* Wfc  = WB + nQKV + nOUT;
  ushort_t* Wprj = WB + nQKV + nOUT + nFC;

  k_conv<<<(int)((nQKV/4 + 255)/256), 256, 0, stream>>>(qkv_w,  Wqkv, (int)(nQKV/4));
  k_conv<<<(int)((nOUT/4 + 255)/256), 256, 0, stream>>>(out_w,  Wout, (int)(nOUT/4));
  k_conv<<<(int)((nFC /4 + 255)/256), 256, 0, stream>>>(fc_w,   Wfc,  (int)(nFC /4));
  k_conv<<<(int)((nPRJ/4 + 255)/256), 256, 0, stream>>>(proj_w, Wprj, (int)(nPRJ/4));

  if (hf32)
    run_all<true >(text, cprompt, tok_emb, pos_emb, Wqkv, qkv_b, Wout, out_b,
                   ln1_w, ln1_b, ln2_w, ln2_b, Wfc, fc_b, Wprj, proj_b,
                   lnf_w, lnf_b, tproj, posy, H, Y, BIG, FI, F,
                   (float*)d_out, sc, stream);
  else
    run_all<false>(text, cprompt, tok_emb, pos_emb, Wqkv, qkv_b, Wout, out_b,
                   ln1_w, ln1_b, ln2_w, ln2_b, Wfc, fc_b, Wprj, proj_b,
                   lnf_w, lnf_b, tproj, posy, H, Y, BIG, FI, F,
                   (float*)d_out, sc, stream);
}

// Round 2
// 17500.089 us; speedup vs baseline: 1.2766x; 1.2766x over previous
//
#include <hip/hip_runtime.h>
#include <math.h>
#include <stdint.h>

#define CTX 77
#define WIDTH 512
#define HEADS 8
#define DH 64
#define LAYERS 12
#define EMBED 1024
#define NTXT 128
#define PP 8
#define LPROMPT 16
#define EOTTOK 49407
#define BSEQ (PP*NTXT)          // 1024
#define ROWS (BSEQ*CTX)         // 78848

typedef unsigned short ushort_t;
typedef __attribute__((ext_vector_type(8))) short short8;
typedef __attribute__((ext_vector_type(4))) float floatx4;

__device__ __forceinline__ float b2f(ushort_t u){
  union { unsigned int i; float f; } x; x.i = ((unsigned int)u) << 16; return x.f;
}
__device__ __forceinline__ ushort_t f2b(float f){
  union { float f; unsigned int i; } x; x.f = f;
  unsigned int r = x.i + 0x7fffu + ((x.i >> 16) & 1u);
  return (ushort_t)(r >> 16);
}
__device__ __forceinline__ float wsum(float v){
  #pragma unroll
  for (int o = 32; o > 0; o >>= 1) v += __shfl_xor(v, o, 64);
  return v;
}
__device__ __forceinline__ float wmax(float v){
  #pragma unroll
  for (int o = 32; o > 0; o >>= 1) v = fmaxf(v, __shfl_xor(v, o, 64));
  return v;
}

// async global->LDS, 16 B per lane; LDS dest = wave-uniform base + lane*16.
// Casts go through uintptr_t (generic LDS pointer low 32 bits == LDS offset).
__device__ __forceinline__ void async16(const void* g, void* l){
  __builtin_amdgcn_global_load_lds(
      (const __attribute__((address_space(1))) void*)(uintptr_t)g,
      (__attribute__((address_space(3))) void*)(uint32_t)(uintptr_t)l,
      16, 0, 0);
}

// -------- fp32 -> bf16 weight conversion (RNE), 4 elems/thread --------
__global__ __launch_bounds__(256) void k_conv(
    const float* __restrict__ s, ushort_t* __restrict__ d, int n4)
{
  int i = blockIdx.x * 256 + threadIdx.x;
  if (i < n4){
    float4 v = ((const float4*)s)[i];
    ushort_t o[4] = { f2b(v.x), f2b(v.y), f2b(v.z), f2b(v.w) };
    ((int2*)d)[i] = *(int2*)o;
  }
}

// -------- pos_y: first EOT position per text row --------
__global__ void k_posy(const int* __restrict__ text, int* __restrict__ posy){
  int n = threadIdx.x;
  if (n < NTXT){
    int p = 0;
    for (int t = 0; t < CTX; ++t){ if (text[n*CTX + t] == EOTTOK){ p = t; break; } }
    posy[n] = p;
  }
}

// -------- embedding + prompt splice + pos_emb -> H --------
template<bool RF32>
__global__ __launch_bounds__(256) void k_embed(
    const int* __restrict__ text, const float* __restrict__ cprompt,
    const float* __restrict__ tok_emb, const float* __restrict__ pos_emb,
    const int* __restrict__ posy, void* __restrict__ Hp)
{
  long long idx = (long long)blockIdx.x * 256 + threadIdx.x;
  int d   = (int)(idx & 511);
  int row = (int)(idx >> 9);
  int t  = row % CTX;
  int pn = row / CTX;
  int n  = pn % NTXT;
  int p  = pn / NTXT;
  int py = posy[n];
  float v;
  if (t >= py && t < py + LPROMPT){
    int pidx = t - py;
    v = cprompt[(p*LPROMPT + pidx)*WIDTH + d];
  } else {
    int src = (t < py) ? t : (t - LPROMPT + 1);
    src = min(max(src, 0), CTX-1);
    int tok = text[n*CTX + src];
    v = tok_emb[(long long)tok*WIDTH + d];
  }
  v += pos_emb[t*WIDTH + d];
  if constexpr (RF32) ((float*)Hp)[idx] = v;
  else                ((ushort_t*)Hp)[idx] = f2b(v);
}

// -------- LayerNorm: H -> Y(bf16), one wave per 512-row --------
template<bool RF32>
__global__ __launch_bounds__(256) void k_ln(
    const void* __restrict__ Hp, const float* __restrict__ w,
    const float* __restrict__ b, ushort_t* __restrict__ Y, int nrows)
{
  int wid = threadIdx.x >> 6, lane = threadIdx.x & 63;
  int row = blockIdx.x * 4 + wid;
  if (row >= nrows) return;
  float v[8];
  if constexpr (RF32){
    const float* x = (const float*)Hp + (long long)row * WIDTH;
    #pragma unroll
    for (int i = 0; i < 8; ++i) v[i] = x[lane*8 + i];
  } else {
    const ushort_t* x = (const ushort_t*)Hp + (long long)row * WIDTH;
    int4 raw = *(const int4*)(x + lane*8);
    ushort_t* u = (ushort_t*)&raw;
    #pragma unroll
    for (int i = 0; i < 8; ++i) v[i] = b2f(u[i]);
  }
  float s = 0.f, ss = 0.f;
  #pragma unroll
  for (int i = 0; i < 8; ++i){ s += v[i]; ss += v[i]*v[i]; }
  s = wsum(s); ss = wsum(ss);
  float mean = s * (1.0f/WIDTH);
  float var  = ss * (1.0f/WIDTH) - mean*mean;
  float rs = rsqrtf(var + 1e-5f);
  ushort_t o[8];
  #pragma unroll
  for (int i = 0; i < 8; ++i){
    int d = lane*8 + i;
    o[i] = f2b((v[i]-mean)*rs*w[d] + b[d]);
  }
  *(int4*)(Y + (long long)row*WIDTH + lane*8) = *(int4*)o;
}

// ============================================================================
// GEMM: C[M,N] = A[M,K](bf16) @ W[N,K]^T(bf16) + bias(fp32)
// m97-class structure, 128x128 tile, BK=64 (halves barrier/drain events per
// FLOP vs BK=32; LDS stays 32 KiB -> occupancy unchanged at ~3 blocks/CU).
// BK=64 rows are 128 B => naive ds_read_b128 would be a 16-way bank conflict,
// so the 3-bit XOR swizzle (verified in R0) is applied: LDS write stays
// LINEAR (global_load_lds requirement), the global SOURCE k-chunk is
// pre-swizzled by row, and reads XOR the same involution:
//   stage: thread t -> row t>>3, chunk ((t ^ (t>>3)) & 7)
//   read:  elem col = (s*32 + quad*8) ^ ((r & 7) * 8)
// After swizzle a quad's 16 lanes touch each 16B slot exactly twice = 2-way
// aliasing = free (m136).
// MODE 0: O=bf16(acc+bias)  MODE 1: O=bf16(gelu(acc+bias))  MODE 2: H += acc+bias
// ============================================================================
template<int MODE, bool RF32>
__global__ __launch_bounds__(256) void k_gemm(
    const ushort_t* __restrict__ A, const ushort_t* __restrict__ W,
    const float* __restrict__ bias, void* __restrict__ Hp,
    ushort_t* __restrict__ O, int K, int N)
{
  __shared__ ushort_t As[128*64];   // 16 KiB
  __shared__ ushort_t Bs[128*64];   // 16 KiB
  int tid  = threadIdx.x;
  int lane = tid & 63, wid = tid >> 6;
  int wm = wid >> 1, wn = wid & 1;
  long long m0 = (long long)blockIdx.y * 128;
  int n0 = blockIdx.x * 128;

  floatx4 acc[4][4];
  #pragma unroll
  for (int i = 0; i < 4; ++i)
    #pragma unroll
    for (int j = 0; j < 4; ++j){ floatx4 z = {0.f,0.f,0.f,0.f}; acc[i][j] = z; }

  // staging geometry: 4 rounds of 32 rows per matrix; round q, thread t
  // covers row q*32 + (t>>3), swizzled 8-elem chunk ((t^(t>>3))&7).
  // Wave w's 64 lanes within a round cover rows [w*8, w*8+8) x full 128 B
  // -> LDS dest linear = base + q*2048 + w*512 (elems) + lane*16 B.
  const int srow = tid >> 3;                       // 0..31
  const int sc8  = ((tid ^ (tid >> 3)) & 7) * 8;   // pre-swizzled k-chunk
  const ushort_t* gA = A + (m0 + srow) * (long long)K + sc8;
  const ushort_t* gB = W + ((size_t)n0 + srow) * K + sc8;
  const size_t qstep = (size_t)32 * K;             // 32 rows
  const int lbase = wid * 512;                     // elems

  const int quad = lane >> 4, r = lane & 15;
  const int swz = (r & 7) * 8;                     // read-side XOR (elems)

  for (int k0 = 0; k0 < K; k0 += 64){
    __syncthreads();                 // prev iter's LDS reads done
    #pragma unroll
    for (int q = 0; q < 4; ++q){
      async16(gA + q*qstep, As + q*2048 + lbase);
      async16(gB + q*qstep, Bs + q*2048 + lbase);
    }
    gA += 64; gB += 64;
    __syncthreads();                 // staging drained (vmcnt0 before barrier)
    #pragma unroll
    for (int s = 0; s < 2; ++s){
      const int co = (s*32 + quad*8) ^ swz;
      short8 af[4], bf[4];
      #pragma unroll
      for (int i = 0; i < 4; ++i) af[i] = *(const short8*)(As + (wm*64 + i*16 + r)*64 + co);
      #pragma unroll
      for (int j = 0; j < 4; ++j) bf[j] = *(const short8*)(Bs + (wn*64 + j*16 + r)*64 + co);
      #pragma unroll
      for (int i = 0; i < 4; ++i)
        #pragma unroll
        for (int j = 0; j < 4; ++j)
          acc[i][j] = __builtin_amdgcn_mfma_f32_16x16x32_bf16(af[i], bf[j], acc[i][j], 0, 0, 0);
    }
  }

  int cn = lane & 15;
  #pragma unroll
  for (int i = 0; i < 4; ++i){
    #pragma unroll
    for (int j = 0; j < 4; ++j){
      int gcol = n0 + wn*64 + j*16 + cn;
      float bv = bias[gcol];
      #pragma unroll
      for (int rg = 0; rg < 4; ++rg){
        long long grow = m0 + wm*64 + i*16 + quad*4 + rg;
        float v = acc[i][j][rg] + bv;
        if (MODE == 0){
          O[grow*N + gcol] = f2b(v);
        } else if (MODE == 1){
          float g = v / (1.0f + __expf(-1.702f*v));
          O[grow*N + gcol] = f2b(g);
        } else {
          long long idx = grow*N + gcol;
          if constexpr (RF32) ((float*)Hp)[idx] += v;
          else { ushort_t* hb = (ushort_t*)Hp; hb[idx] = f2b(b2f(hb[idx]) + v); }
        }
      }
    }
  }
}

// -------- MFMA causal attention: one block per (seq b, head h) --------
__global__ __launch_bounds__(256) void k_attn(
    const ushort_t* __restrict__ QKV, ushort_t* __restrict__ Y)
{
  __shared__ char smem[55872];
  ushort_t* Qs = (ushort_t*)smem;
  ushort_t* Ks = (ushort_t*)(smem + 11520);
  float*    Ss = (float*)smem;
  ushort_t* Vt = (ushort_t*)(smem + 25920);
  ushort_t* Ps = (ushort_t*)(smem + 39232);

  int b = blockIdx.x >> 3, h = blockIdx.x & 7;
  int tid = threadIdx.x;
  int lane = tid & 63, wid = tid >> 6;
  int quad = lane >> 4, r = lane & 15;
  const ushort_t* base = QKV + (size_t)b*CTX*1536 + h*64;

  #pragma unroll
  for (int it = 0; it < 5; ++it){
    int id = tid + it*256;            // 0..1279 = 80 rows * 16 chunks
    int t  = id >> 4;
    int d4 = (id & 15) * 4;
    ushort_t q[4], k[4], v[4];
    if (t < CTX){
      const ushort_t* rp = base + (size_t)t*1536 + d4;
      *(int2*)q = *(const int2*)(rp);
      *(int2*)k = *(const int2*)(rp + 512);
      *(int2*)v = *(const int2*)(rp + 1024);
    } else {
      q[0]=q[1]=q[2]=q[3]=0; k[0]=k[1]=k[2]=k[3]=0; v[0]=v[1]=v[2]=v[3]=0;
    }
    *(int2*)(Qs + t*72 + d4) = *(int2*)q;
    *(int2*)(Ks + t*72 + d4) = *(int2*)k;
    #pragma unroll
    for (int i = 0; i < 4; ++i) Vt[(d4+i)*104 + t] = v[i];
  }
  { // zero Vt key-columns 80..95
    int z = tid * 4;
    int d = z >> 4, c = 80 + (z & 15);
    ushort_t zz[4] = {0,0,0,0};
    *(int2*)(Vt + d*104 + c) = *(int2*)zz;
  }
  __syncthreads();

  const int TI[15] = {0,1,1,2,2,2,3,3,3,3,4,4,4,4,4};
  const int TJ[15] = {0,0,1,0,1,2,0,1,2,3,0,1,2,3,4};
  floatx4 cS[4];
  int ntile = 0;
  for (int tt = wid; tt < 15; tt += 4, ++ntile){
    int i = TI[tt], j = TJ[tt];
    floatx4 c = {0.f,0.f,0.f,0.f};
    #pragma unroll
    for (int s = 0; s < 2; ++s){
      short8 aq = *(const short8*)(Qs + (i*16 + r)*72 + s*32 + quad*8);
      short8 bk = *(const short8*)(Ks + (j*16 + r)*72 + s*32 + quad*8);
      c = __builtin_amdgcn_mfma_f32_16x16x32_bf16(aq, bk, c, 0, 0, 0);
    }
    cS[ntile] = c;
  }
  __syncthreads();

  {
    int idx = 0;
    for (int tt = wid; tt < 15; tt += 4, ++idx){
      int i = TI[tt], j = TJ[tt];
      #pragma unroll
      for (int rg = 0; rg < 4; ++rg){
        int q  = i*16 + quad*4 + rg;
        int kk = j*16 + r;
        float s = cS[idx][rg] * 0.125f;
        if (kk > q) s = -1e30f;
        Ss[q*81 + kk] = s;
      }
    }
  }
  __syncthreads();

  for (int q = wid; q < 80; q += 4){
    if (q >= CTX){
      Ps[q*104 + lane] = 0;
      if (lane < 32) Ps[q*104 + 64 + lane] = 0;
      continue;
    }
    int k1 = 64 + lane;
    float s0 = (lane <= q) ? Ss[q*81 + lane] : -1e30f;
    float s1 = (k1  <= q) ? Ss[q*81 + k1 ]  : -1e30f;
    float mx = wmax(fmaxf(s0, s1));
    float e0 = (lane <= q) ? __expf(s0 - mx) : 0.0f;
    float e1 = (k1  <= q) ? __expf(s1 - mx) : 0.0f;
    float inv = 1.0f / wsum(e0 + e1);
    Ps[q*104 + lane] = f2b(e0 * inv);
    if (lane < 32) Ps[q*104 + 64 + lane] = f2b(e1 * inv);
  }
  __syncthreads();

  for (int tt = wid; tt < 20; tt += 4){
    int mi = tt >> 2, ni = tt & 3;
    floatx4 c = {0.f,0.f,0.f,0.f};
    #pragma unroll
    for (int kc = 0; kc < 3; ++kc){
      short8 ap = *(const short8*)(Ps + (mi*16 + r)*104 + kc*32 + quad*8);
      short8 bv = *(const short8*)(Vt + (ni*16 + r)*104 + kc*32 + quad*8);
      c = __builtin_amdgcn_mfma_f32_16x16x32_bf16(ap, bv, c, 0, 0, 0);
    }
    #pragma unroll
    for (int rg = 0; rg < 4; ++rg){
      int q = mi*16 + quad*4 + rg;
      if (q < CTX)
        Y[((size_t)b*CTX + q)*WIDTH + h*64 + ni*16 + r] = f2b(c[rg]);
    }
  }
}

// -------- gather EOT+LP-1 rows, final LN -> FI (bf16 [1024,512]) --------
template<bool RF32>
__global__ __launch_bounds__(256) void k_lnf_gather(
    const void* __restrict__ Hp, const int* __restrict__ posy,
    const float* __restrict__ w, const float* __restrict__ b,
    ushort_t* __restrict__ FI)
{
  int wid = threadIdx.x >> 6, lane = threadIdx.x & 63;
  int rr = blockIdx.x * 4 + wid;
  if (rr >= BSEQ) return;
  int n = rr % NTXT;
  int tok = posy[n] + LPROMPT - 1;
  long long row = (long long)rr*CTX + tok;
  float v[8];
  if constexpr (RF32){
    const float* x = (const float*)Hp + row * WIDTH;
    #pragma unroll
    for (int i = 0; i < 8; ++i) v[i] = x[lane*8 + i];
  } else {
    const ushort_t* x = (const ushort_t*)Hp + row * WIDTH;
    int4 raw = *(const int4*)(x + lane*8);
    ushort_t* u = (ushort_t*)&raw;
    #pragma unroll
    for (int i = 0; i < 8; ++i) v[i] = b2f(u[i]);
  }
  float s = 0.f, ss = 0.f;
  #pragma unroll
  for (int i = 0; i < 8; ++i){ s += v[i]; ss += v[i]*v[i]; }
  s = wsum(s); ss = wsum(ss);
  float mean = s * (1.0f/WIDTH);
  float var  = ss * (1.0f/WIDTH) - mean*mean;
  float rs = rsqrtf(var + 1e-5f);
  ushort_t o[8];
  #pragma unroll
  for (int i = 0; i < 8; ++i){
    int d = lane*8 + i;
    o[i] = f2b((v[i]-mean)*rs*w[d] + b[d]);
  }
  *(int4*)(FI + (long long)rr*WIDTH + lane*8) = *(int4*)o;
}

// -------- final projection: F[1024,1024] = FI[1024,512](bf16) @ TP[512,1024](fp32) --------
__global__ __launch_bounds__(256) void k_fproj(
    const ushort_t* __restrict__ FI, const float* __restrict__ TP,
    float* __restrict__ F)
{
  int idx = blockIdx.x * 256 + threadIdx.x;
  int e = idx & (EMBED-1);
  int m = idx >> 10;
  float acc = 0.f;
  #pragma unroll 8
  for (int k = 0; k < WIDTH; ++k)
    acc += b2f(FI[m*WIDTH + k]) * TP[k*EMBED + e];
  F[idx] = acc;
}

// -------- per-row L2 normalize in place --------
__global__ __launch_bounds__(256) void k_rownorm(float* __restrict__ F)
{
  __shared__ float red[4];
  int rr = blockIdx.x;
  float* x = F + (long long)rr*EMBED;
  float ss = 0.f;
  for (int i = threadIdx.x; i < EMBED; i += 256){ float v = x[i]; ss += v*v; }
  ss = wsum(ss);
  int wid = threadIdx.x >> 6, lane = threadIdx.x & 63;
  if (lane == 0) red[wid] = ss;
  __syncthreads();
  float inv = rsqrtf(red[0]+red[1]+red[2]+red[3]);
  for (int i = threadIdx.x; i < EMBED; i += 256) x[i] *= inv;
}

// -------- mean over n, normalize, write fp32 out --------
__global__ __launch_bounds__(256) void k_meannorm(
    const float* __restrict__ F, float* __restrict__ OUT)
{
  __shared__ float red[4];
  int p = blockIdx.x;
  float m[4]; float ss = 0.f;
  #pragma unroll
  for (int j = 0; j < 4; ++j){
    int e = threadIdx.x + j*256;
    float s = 0.f;
    for (int n = 0; n < NTXT; ++n) s += F[((long long)(p*NTXT + n))*EMBED + e];
    s *= (1.0f/NTXT);
    m[j] = s; ss += s*s;
  }
  ss = wsum(ss);
  int wid = threadIdx.x >> 6, lane = threadIdx.x & 63;
  if (lane == 0) red[wid] = ss;
  __syncthreads();
  float inv = rsqrtf(red[0]+red[1]+red[2]+red[3]);
  #pragma unroll
  for (int j = 0; j < 4; ++j)
    OUT[p*EMBED + threadIdx.x + j*256] = m[j]*inv;
}

// ============================ launcher ============================

template<bool RF32>
static void run_all(const int* text, const float* cprompt, const float* tok_emb,
                    const float* pos_emb,
                    const ushort_t* Wqkv, const float* qkv_b,
                    const ushort_t* Wout, const float* out_b,
                    const float* ln1_w, const float* ln1_b,
                    const float* ln2_w, const float* ln2_b,
                    const ushort_t* Wfc, const float* fc_b,
                    const ushort_t* Wproj, const float* proj_b,
                    const float* lnf_w, const float* lnf_b, const float* tproj,
                    int* posy, void* H, ushort_t* Y, ushort_t* BIG,
                    ushort_t* FI, float* F, float* OUT, int sc, hipStream_t stream)
{
  const int rows_c = ROWS / sc;       // multiple of 128 for sc in {1,2,4,8}
  const int seqs_c = BSEQ / sc;

  k_posy<<<1, 128, 0, stream>>>(text, posy);
  k_embed<RF32><<<(ROWS*512)/256, 256, 0, stream>>>(text, cprompt, tok_emb, pos_emb, posy, H);

  for (int L = 0; L < LAYERS; ++L){
    k_ln<RF32><<<ROWS/4, 256, 0, stream>>>(H, ln1_w + L*WIDTH, ln1_b + L*WIDTH, Y, ROWS);
    for (int c = 0; c < sc; ++c){
      size_t r0 = (size_t)c * rows_c;
      k_gemm<0,RF32><<<dim3(12, rows_c/128), 256, 0, stream>>>(
          Y + r0*WIDTH, Wqkv + (size_t)L*1536*512, qkv_b + L*1536,
          nullptr, BIG, 512, 1536);
      k_attn<<<seqs_c*HEADS, 256, 0, stream>>>(BIG, Y + r0*WIDTH);
    }
    k_gemm<2,RF32><<<dim3(4, ROWS/128), 256, 0, stream>>>(
        Y, Wout + (size_t)L*512*512, out_b + L*512, H, nullptr, 512, 512);
    k_ln<RF32><<<ROWS/4, 256, 0, stream>>>(H, ln2_w + L*WIDTH, ln2_b + L*WIDTH, Y, ROWS);
    for (int c = 0; c < sc; ++c){
      size_t r0 = (size_t)c * rows_c;
      void* Hoff = RF32 ? (void*)((float*)H + r0*WIDTH) : (void*)((ushort_t*)H + r0*WIDTH);
      k_gemm<1,RF32><<<dim3(16, rows_c/128), 256, 0, stream>>>(
          Y + r0*WIDTH, Wfc + (size_t)L*2048*512, fc_b + L*2048,
          nullptr, BIG, 512, 2048);
      k_gemm<2,RF32><<<dim3(4, rows_c/128), 256, 0, stream>>>(
          BIG, Wproj + (size_t)L*512*2048, proj_b + L*512, Hoff, nullptr, 2048, 512);
    }
  }

  k_lnf_gather<RF32><<<BSEQ/4, 256, 0, stream>>>(H, posy, lnf_w, lnf_b, FI);
  k_fproj<<<(BSEQ*EMBED)/256, 256, 0, stream>>>(FI, tproj, F);
  k_rownorm<<<BSEQ, 256, 0, stream>>>(F);
  k_meannorm<<<PP, 256, 0, stream>>>(F, OUT);
}

extern "C" void kernel_launch(void* const* d_in, const int* in_sizes, int n_in,
                              void* d_out, int out_size, void* d_ws, size_t ws_size,
                              hipStream_t stream)
{
  const int*   text    = (const int*)d_in[0];
  const float* cprompt = (const float*)d_in[1];
  const float* tok_emb = (const float*)d_in[2];
  const float* pos_emb = (const float*)d_in[3];
  const float* qkv_w   = (const float*)d_in[4];
  const float* qkv_b   = (const float*)d_in[5];
  const float* out_w   = (const float*)d_in[6];
  const float* out_b   = (const float*)d_in[7];
  const float* ln1_w   = (const float*)d_in[8];
  const float* ln1_b   = (const float*)d_in[9];
  const float* ln2_w   = (const float*)d_in[10];
  const float* ln2_b   = (const float*)d_in[11];
  const float* fc_w    = (const float*)d_in[12];
  const float* fc_b    = (const float*)d_in[13];
  const float* proj_w  = (const float*)d_in[14];
  const float* proj_b  = (const float*)d_in[15];
  const float* lnf_w   = (const float*)d_in[16];
  const float* lnf_b   = (const float*)d_in[17];
  const float* tproj   = (const float*)d_in[18];

  const size_t nQKV = (size_t)LAYERS*1536*512;
  const size_t nOUT = (size_t)LAYERS*512*512;
  const size_t nFC  = (size_t)LAYERS*2048*512;
  const size_t nPRJ = (size_t)LAYERS*512*2048;
  const size_t nWB  = nQKV + nOUT + nFC + nPRJ;

  auto al = [](size_t b){ return (b + 255) & ~(size_t)255; };
  const size_t fixed = al(NTXT*sizeof(int)) + al((size_t)ROWS*WIDTH*2 /*Y*/)
                     + al((size_t)BSEQ*WIDTH*2 /*FI*/) + al((size_t)BSEQ*EMBED*4 /*F*/)
                     + al(nWB*2);
  int sc = 8; bool hf32 = false;
  const int scs[4] = {1, 2, 4, 8};
  bool found = false;
  for (int pass = 0; pass < 2 && !found; ++pass){
    size_t hbytes = (size_t)ROWS*WIDTH*(pass == 0 ? 4 : 2);
    for (int i = 0; i < 4; ++i){
      size_t big = (size_t)(ROWS/scs[i]) * 2048 * 2;
      if (fixed + al(hbytes) + al(big) <= ws_size){
        sc = scs[i]; hf32 = (pass == 0); found = true; break;
      }
    }
  }

  char* ws = (char*)d_ws;
  size_t off = 0;
  auto alloc = [&](size_t bytes)->char*{
    char* pp = ws + off; off += (bytes + 255) & ~(size_t)255; return pp;
  };
  int*      posy = (int*)     alloc(NTXT*sizeof(int));
  void*     H    = (void*)    alloc((size_t)ROWS*WIDTH*(hf32 ? 4 : 2));
  ushort_t* Y    = (ushort_t*)alloc((size_t)ROWS*WIDTH*2);
  ushort_t* BIG  = (ushort_t*)alloc((size_t)(ROWS/sc)*2048*2);
  ushort_t* FI   = (ushort_t*)alloc((size_t)BSEQ*WIDTH*2);
  float*    F    = (float*)   alloc((size_t)BSEQ*EMBED*4);
  ushort_t* WB   = (ushort_t*)alloc(nWB*2);
  ushort_t* Wqkv = WB;
  ushort_t* Wout = WB + nQKV;
  ushort_t* Wfc  = WB + nQKV + nOUT;
  ushort_t* Wprj = WB + nQKV + nOUT + nFC;

  k_conv<<<(int)((nQKV/4 + 255)/256), 256, 0, stream>>>(qkv_w,  Wqkv, (int)(nQKV/4));
  k_conv<<<(int)((nOUT/4 + 255)/256), 256, 0, stream>>>(out_w,  Wout, (int)(nOUT/4));
  k_conv<<<(int)((nFC /4 + 255)/256), 256, 0, stream>>>(fc_w,   Wfc,  (int)(nFC /4));
  k_conv<<<(int)((nPRJ/4 + 255)/256), 256, 0, stream>>>(proj_w, Wprj, (int)(nPRJ/4));

  if (hf32)
    run_all<true >(text, cprompt, tok_emb, pos_emb, Wqkv, qkv_b, Wout, out_b,
                   ln1_w, ln1_b, ln2_w, ln2_b, Wfc, fc_b, Wprj, proj_b,
                   lnf_w, lnf_b, tproj, posy, H, Y, BIG, FI, F,
                   (float*)d_out, sc, stream);
  else
    run_all<false>(text, cprompt, tok_emb, pos_emb, Wqkv, qkv_b, Wout, out_b,
                   ln1_w, ln1_b, ln2_w, ln2_b, Wfc, fc_b, Wprj, proj_b,
                   lnf_w, lnf_b, tproj, posy, H, Y, BIG, FI, F,
                   (float*)d_out, sc, stream);
}

// Round 3
// 15049.930 us; speedup vs baseline: 1.4844x; 1.1628x over previous
//
#include <hip/hip_runtime.h>
#include <math.h>
#include <stdint.h>

#define CTX 77
#define WIDTH 512
#define HEADS 8
#define DH 64
#define LAYERS 12
#define EMBED 1024
#define NTXT 128
#define PP 8
#define LPROMPT 16
#define EOTTOK 49407
#define BSEQ (PP*NTXT)          // 1024
#define ROWS (BSEQ*CTX)         // 78848

typedef unsigned short ushort_t;
typedef __attribute__((ext_vector_type(8))) short short8;
typedef __attribute__((ext_vector_type(4))) float floatx4;

__device__ __forceinline__ float b2f(ushort_t u){
  union { unsigned int i; float f; } x; x.i = ((unsigned int)u) << 16; return x.f;
}
__device__ __forceinline__ ushort_t f2b(float f){
  union { float f; unsigned int i; } x; x.f = f;
  unsigned int r = x.i + 0x7fffu + ((x.i >> 16) & 1u);
  return (ushort_t)(r >> 16);
}
__device__ __forceinline__ float wsum(float v){
  #pragma unroll
  for (int o = 32; o > 0; o >>= 1) v += __shfl_xor(v, o, 64);
  return v;
}
__device__ __forceinline__ float wmax(float v){
  #pragma unroll
  for (int o = 32; o > 0; o >>= 1) v = fmaxf(v, __shfl_xor(v, o, 64));
  return v;
}

// async global->LDS, 16 B per lane; LDS dest = wave-uniform base + lane*16.
__device__ __forceinline__ void async16(const void* g, void* l){
  __builtin_amdgcn_global_load_lds(
      (const __attribute__((address_space(1))) void*)(uintptr_t)g,
      (__attribute__((address_space(3))) void*)(uint32_t)(uintptr_t)l,
      16, 0, 0);
}

// -------- fp32 -> bf16 weight conversion (RNE), 4 elems/thread --------
__global__ __launch_bounds__(256) void k_conv(
    const float* __restrict__ s, ushort_t* __restrict__ d, int n4)
{
  int i = blockIdx.x * 256 + threadIdx.x;
  if (i < n4){
    float4 v = ((const float4*)s)[i];
    ushort_t o[4] = { f2b(v.x), f2b(v.y), f2b(v.z), f2b(v.w) };
    ((int2*)d)[i] = *(int2*)o;
  }
}

// -------- pos_y: first EOT position per text row --------
__global__ void k_posy(const int* __restrict__ text, int* __restrict__ posy){
  int n = threadIdx.x;
  if (n < NTXT){
    int p = 0;
    for (int t = 0; t < CTX; ++t){ if (text[n*CTX + t] == EOTTOK){ p = t; break; } }
    posy[n] = p;
  }
}

// -------- embedding + prompt splice + pos_emb -> H, 8 elems/thread --------
template<bool RF32>
__global__ __launch_bounds__(256) void k_embed(
    const int* __restrict__ text, const float* __restrict__ cprompt,
    const float* __restrict__ tok_emb, const float* __restrict__ pos_emb,
    const int* __restrict__ posy, void* __restrict__ Hp)
{
  long long idx = (long long)blockIdx.x * 256 + threadIdx.x;  // d8-chunk id
  int d8  = (int)(idx & 63) * 8;
  int row = (int)(idx >> 6);
  int t  = row % CTX;
  int pn = row / CTX;
  int n  = pn % NTXT;
  int p  = pn / NTXT;
  int py = posy[n];
  const float* src;
  if (t >= py && t < py + LPROMPT){
    src = cprompt + ((p*LPROMPT + (t - py))*WIDTH + d8);
  } else {
    int s0 = (t < py) ? t : (t - LPROMPT + 1);
    s0 = min(max(s0, 0), CTX-1);
    int tok = text[n*CTX + s0];
    src = tok_emb + ((long long)tok*WIDTH + d8);
  }
  const float* pe = pos_emb + (t*WIDTH + d8);
  float4 a0 = *(const float4*)(src);
  float4 a1 = *(const float4*)(src + 4);
  float4 b0 = *(const float4*)(pe);
  float4 b1 = *(const float4*)(pe + 4);
  float v[8] = { a0.x+b0.x, a0.y+b0.y, a0.z+b0.z, a0.w+b0.w,
                 a1.x+b1.x, a1.y+b1.y, a1.z+b1.z, a1.w+b1.w };
  long long base = (long long)row*WIDTH + d8;
  if constexpr (RF32){
    float4 o0 = {v[0],v[1],v[2],v[3]};
    float4 o1 = {v[4],v[5],v[6],v[7]};
    *(float4*)((float*)Hp + base)     = o0;
    *(float4*)((float*)Hp + base + 4) = o1;
  } else {
    ushort_t o[8];
    #pragma unroll
    for (int i = 0; i < 8; ++i) o[i] = f2b(v[i]);
    *(int4*)((ushort_t*)Hp + base) = *(int4*)o;
  }
}

// -------- LayerNorm: H -> Y(bf16), one wave per 512-row --------
template<bool RF32>
__global__ __launch_bounds__(256) void k_ln(
    const void* __restrict__ Hp, const float* __restrict__ w,
    const float* __restrict__ b, ushort_t* __restrict__ Y, int nrows)
{
  int wid = threadIdx.x >> 6, lane = threadIdx.x & 63;
  int row = blockIdx.x * 4 + wid;
  if (row >= nrows) return;
  float v[8];
  if constexpr (RF32){
    const float* x = (const float*)Hp + (long long)row * WIDTH;
    #pragma unroll
    for (int i = 0; i < 8; ++i) v[i] = x[lane*8 + i];
  } else {
    const ushort_t* x = (const ushort_t*)Hp + (long long)row * WIDTH;
    int4 raw = *(const int4*)(x + lane*8);
    ushort_t* u = (ushort_t*)&raw;
    #pragma unroll
    for (int i = 0; i < 8; ++i) v[i] = b2f(u[i]);
  }
  float s = 0.f, ss = 0.f;
  #pragma unroll
  for (int i = 0; i < 8; ++i){ s += v[i]; ss += v[i]*v[i]; }
  s = wsum(s); ss = wsum(ss);
  float mean = s * (1.0f/WIDTH);
  float var  = ss * (1.0f/WIDTH) - mean*mean;
  float rs = rsqrtf(var + 1e-5f);
  ushort_t o[8];
  #pragma unroll
  for (int i = 0; i < 8; ++i){
    int d = lane*8 + i;
    o[i] = f2b((v[i]-mean)*rs*w[d] + b[d]);
  }
  *(int4*)(Y + (long long)row*WIDTH + lane*8) = *(int4*)o;
}

// ============================================================================
// GEMM: C[M,N] = A[M,K](bf16) @ W[N,K]^T(bf16) + bias(fp32)
// 128x128 tile, BK=64, both-sides XOR swizzle (R1-verified), launch_bounds
// (256,4) pins 4 blocks/CU (VGPR<=128; acc 64 + frags 32 + addr ~20 fits).
// MODE 0: O=bf16(acc+bias)  MODE 1: O=bf16(gelu(acc+bias))  MODE 2: H += acc+bias
// ============================================================================
template<int MODE, bool RF32>
__global__ __launch_bounds__(256, 4) void k_gemm(
    const ushort_t* __restrict__ A, const ushort_t* __restrict__ W,
    const float* __restrict__ bias, void* __restrict__ Hp,
    ushort_t* __restrict__ O, int K, int N)
{
  __shared__ ushort_t As[128*64];   // 16 KiB
  __shared__ ushort_t Bs[128*64];   // 16 KiB
  int tid  = threadIdx.x;
  int lane = tid & 63, wid = tid >> 6;
  int wm = wid >> 1, wn = wid & 1;
  long long m0 = (long long)blockIdx.y * 128;
  int n0 = blockIdx.x * 128;

  floatx4 acc[4][4];
  #pragma unroll
  for (int i = 0; i < 4; ++i)
    #pragma unroll
    for (int j = 0; j < 4; ++j){ floatx4 z = {0.f,0.f,0.f,0.f}; acc[i][j] = z; }

  const int srow = tid >> 3;                       // 0..31
  const int sc8  = ((tid ^ (tid >> 3)) & 7) * 8;   // pre-swizzled k-chunk
  const ushort_t* gA = A + (m0 + srow) * (long long)K + sc8;
  const ushort_t* gB = W + ((size_t)n0 + srow) * K + sc8;
  const size_t qstep = (size_t)32 * K;             // 32 rows
  const int lbase = wid * 512;                     // elems

  const int quad = lane >> 4, r = lane & 15;
  const int swz = (r & 7) * 8;                     // read-side XOR (elems)

  for (int k0 = 0; k0 < K; k0 += 64){
    __syncthreads();                 // prev iter's LDS reads done
    #pragma unroll
    for (int q = 0; q < 4; ++q){
      async16(gA + q*qstep, As + q*2048 + lbase);
      async16(gB + q*qstep, Bs + q*2048 + lbase);
    }
    gA += 64; gB += 64;
    __syncthreads();                 // staging drained (vmcnt0 before barrier)
    #pragma unroll
    for (int s = 0; s < 2; ++s){
      const int co = (s*32 + quad*8) ^ swz;
      short8 af[4], bf[4];
      #pragma unroll
      for (int i = 0; i < 4; ++i) af[i] = *(const short8*)(As + (wm*64 + i*16 + r)*64 + co);
      #pragma unroll
      for (int j = 0; j < 4; ++j) bf[j] = *(const short8*)(Bs + (wn*64 + j*16 + r)*64 + co);
      #pragma unroll
      for (int i = 0; i < 4; ++i)
        #pragma unroll
        for (int j = 0; j < 4; ++j)
          acc[i][j] = __builtin_amdgcn_mfma_f32_16x16x32_bf16(af[i], bf[j], acc[i][j], 0, 0, 0);
    }
  }

  int cn = lane & 15;
  #pragma unroll
  for (int i = 0; i < 4; ++i){
    #pragma unroll
    for (int j = 0; j < 4; ++j){
      int gcol = n0 + wn*64 + j*16 + cn;
      float bv = bias[gcol];
      #pragma unroll
      for (int rg = 0; rg < 4; ++rg){
        long long grow = m0 + wm*64 + i*16 + quad*4 + rg;
        float v = acc[i][j][rg] + bv;
        if (MODE == 0){
          O[grow*N + gcol] = f2b(v);
        } else if (MODE == 1){
          float g = v / (1.0f + __expf(-1.702f*v));
          O[grow*N + gcol] = f2b(g);
        } else {
          long long idx = grow*N + gcol;
          if constexpr (RF32) ((float*)Hp)[idx] += v;
          else { ushort_t* hb = (ushort_t*)Hp; hb[idx] = f2b(b2f(hb[idx]) + v); }
        }
      }
    }
  }
}

// ============================================================================
// MFMA causal attention: one block per (seq b, head h).
// LDS squeezed 55872 -> 53056 B => 3 blocks/CU (was 2).
//   Qs 77x72 bf16 @0      (11088)
//   Ks 77x72 bf16 @11088  (11088, ends 22176)
//   Ss 77x77 f32  @0      (23716; aliases Qs+Ks; writes guarded q<77,kk<77)
//   Vt 64x104 bf16 @23728 (13312; 16B-aligned, stride 104 = 2-way-bank-safe)
//   Ps 77x104 bf16 @37040 (16016, ends 53056)
// Rows 77..79 of Q/K/S/P are garbage-by-construction and provably never
// influence stored output: K-garbage cols masked -1e30 (kk>q), S-row writes
// guarded, PV A-row reads clamped to 76, stores guarded q<CTX.
// ============================================================================
__global__ __launch_bounds__(256, 3) void k_attn(
    const ushort_t* __restrict__ QKV, ushort_t* __restrict__ Y)
{
  __shared__ char smem[53056];
  ushort_t* Qs = (ushort_t*)smem;
  ushort_t* Ks = (ushort_t*)(smem + 11088);
  float*    Ss = (float*)smem;
  ushort_t* Vt = (ushort_t*)(smem + 23728);
  ushort_t* Ps = (ushort_t*)(smem + 37040);

  int b = blockIdx.x >> 3, h = blockIdx.x & 7;
  int tid = threadIdx.x;
  int lane = tid & 63, wid = tid >> 6;
  int quad = lane >> 4, r = lane & 15;
  const ushort_t* base = QKV + (size_t)b*CTX*1536 + h*64;

  #pragma unroll
  for (int it = 0; it < 5; ++it){
    int id = tid + it*256;            // 0..1279 = 80 rows * 16 chunks
    int t  = id >> 4;
    int d4 = (id & 15) * 4;
    ushort_t q[4], k[4], v[4];
    if (t < CTX){
      const ushort_t* rp = base + (size_t)t*1536 + d4;
      *(int2*)q = *(const int2*)(rp);
      *(int2*)k = *(const int2*)(rp + 512);
      *(int2*)v = *(const int2*)(rp + 1024);
      *(int2*)(Qs + t*72 + d4) = *(int2*)q;
      *(int2*)(Ks + t*72 + d4) = *(int2*)k;
    } else {
      v[0]=v[1]=v[2]=v[3]=0;
    }
    #pragma unroll
    for (int i = 0; i < 4; ++i) Vt[(d4+i)*104 + t] = v[i];
  }
  { // zero Vt key-columns 80..95
    int z = tid * 4;
    int d = z >> 4, c = 80 + (z & 15);
    ushort_t zz[4] = {0,0,0,0};
    *(int2*)(Vt + d*104 + c) = *(int2*)zz;
  }
  __syncthreads();

  const int TI[15] = {0,1,1,2,2,2,3,3,3,3,4,4,4,4,4};
  const int TJ[15] = {0,0,1,0,1,2,0,1,2,3,0,1,2,3,4};
  floatx4 cS[4];
  int ntile = 0;
  for (int tt = wid; tt < 15; tt += 4, ++ntile){
    int i = TI[tt], j = TJ[tt];
    floatx4 c = {0.f,0.f,0.f,0.f};
    #pragma unroll
    for (int s = 0; s < 2; ++s){
      short8 aq = *(const short8*)(Qs + (i*16 + r)*72 + s*32 + quad*8);
      short8 bk = *(const short8*)(Ks + (j*16 + r)*72 + s*32 + quad*8);
      c = __builtin_amdgcn_mfma_f32_16x16x32_bf16(aq, bk, c, 0, 0, 0);
    }
    cS[ntile] = c;
  }
  __syncthreads();

  {
    int idx = 0;
    for (int tt = wid; tt < 15; tt += 4, ++idx){
      int i = TI[tt], j = TJ[tt];
      #pragma unroll
      for (int rg = 0; rg < 4; ++rg){
        int q  = i*16 + quad*4 + rg;
        int kk = j*16 + r;
        float s = cS[idx][rg] * 0.125f;
        if (kk > q) s = -1e30f;
        if (q < CTX && kk < CTX) Ss[q*77 + kk] = s;
      }
    }
  }
  __syncthreads();

  for (int q = wid; q < CTX; q += 4){
    int k1 = 64 + lane;
    float s0 = (lane <= q) ? Ss[q*77 + lane] : -1e30f;
    float s1 = (k1  <= q) ? Ss[q*77 + k1 ]  : -1e30f;
    float mx = wmax(fmaxf(s0, s1));
    float e0 = (lane <= q) ? __expf(s0 - mx) : 0.0f;
    float e1 = (k1  <= q) ? __expf(s1 - mx) : 0.0f;
    float inv = 1.0f / wsum(e0 + e1);
    Ps[q*104 + lane] = f2b(e0 * inv);
    if (lane < 32) Ps[q*104 + 64 + lane] = f2b(e1 * inv);
  }
  __syncthreads();

  for (int tt = wid; tt < 20; tt += 4){
    int mi = tt >> 2, ni = tt & 3;
    int arow = min(mi*16 + r, CTX-1);     // clamp garbage rows 77..79
    floatx4 c = {0.f,0.f,0.f,0.f};
    #pragma unroll
    for (int kc = 0; kc < 3; ++kc){
      short8 ap = *(const short8*)(Ps + arow*104 + kc*32 + quad*8);
      short8 bv = *(const short8*)(Vt + (ni*16 + r)*104 + kc*32 + quad*8);
      c = __builtin_amdgcn_mfma_f32_16x16x32_bf16(ap, bv, c, 0, 0, 0);
    }
    #pragma unroll
    for (int rg = 0; rg < 4; ++rg){
      int q = mi*16 + quad*4 + rg;
      if (q < CTX)
        Y[((size_t)b*CTX + q)*WIDTH + h*64 + ni*16 + r] = f2b(c[rg]);
    }
  }
}

// -------- gather EOT+LP-1 rows, final LN -> FI (bf16 [1024,512]) --------
template<bool RF32>
__global__ __launch_bounds__(256) void k_lnf_gather(
    const void* __restrict__ Hp, const int* __restrict__ posy,
    const float* __restrict__ w, const float* __restrict__ b,
    ushort_t* __restrict__ FI)
{
  int wid = threadIdx.x >> 6, lane = threadIdx.x & 63;
  int rr = blockIdx.x * 4 + wid;
  if (rr >= BSEQ) return;
  int n = rr % NTXT;
  int tok = posy[n] + LPROMPT - 1;
  long long row = (long long)rr*CTX + tok;
  float v[8];
  if constexpr (RF32){
    const float* x = (const float*)Hp + row * WIDTH;
    #pragma unroll
    for (int i = 0; i < 8; ++i) v[i] = x[lane*8 + i];
  } else {
    const ushort_t* x = (const ushort_t*)Hp + row * WIDTH;
    int4 raw = *(const int4*)(x + lane*8);
    ushort_t* u = (ushort_t*)&raw;
    #pragma unroll
    for (int i = 0; i < 8; ++i) v[i] = b2f(u[i]);
  }
  float s = 0.f, ss = 0.f;
  #pragma unroll
  for (int i = 0; i < 8; ++i){ s += v[i]; ss += v[i]*v[i]; }
  s = wsum(s); ss = wsum(ss);
  float mean = s * (1.0f/WIDTH);
  float var  = ss * (1.0f/WIDTH) - mean*mean;
  float rs = rsqrtf(var + 1e-5f);
  ushort_t o[8];
  #pragma unroll
  for (int i = 0; i < 8; ++i){
    int d = lane*8 + i;
    o[i] = f2b((v[i]-mean)*rs*w[d] + b[d]);
  }
  *(int4*)(FI + (long long)rr*WIDTH + lane*8) = *(int4*)o;
}

// -------- final projection: F[1024,1024] = FI[1024,512](bf16) @ TP[512,1024](fp32) --------
__global__ __launch_bounds__(256) void k_fproj(
    const ushort_t* __restrict__ FI, const float* __restrict__ TP,
    float* __restrict__ F)
{
  int idx = blockIdx.x * 256 + threadIdx.x;
  int e = idx & (EMBED-1);
  int m = idx >> 10;
  float acc = 0.f;
  #pragma unroll 8
  for (int k = 0; k < WIDTH; ++k)
    acc += b2f(FI[m*WIDTH + k]) * TP[k*EMBED + e];
  F[idx] = acc;
}

// -------- per-row L2 normalize in place --------
__global__ __launch_bounds__(256) void k_rownorm(float* __restrict__ F)
{
  __shared__ float red[4];
  int rr = blockIdx.x;
  float* x = F + (long long)rr*EMBED;
  float ss = 0.f;
  for (int i = threadIdx.x; i < EMBED; i += 256){ float v = x[i]; ss += v*v; }
  ss = wsum(ss);
  int wid = threadIdx.x >> 6, lane = threadIdx.x & 63;
  if (lane == 0) red[wid] = ss;
  __syncthreads();
  float inv = rsqrtf(red[0]+red[1]+red[2]+red[3]);
  for (int i = threadIdx.x; i < EMBED; i += 256) x[i] *= inv;
}

// -------- mean over n, normalize, write fp32 out --------
__global__ __launch_bounds__(256) void k_meannorm(
    const float* __restrict__ F, float* __restrict__ OUT)
{
  __shared__ float red[4];
  int p = blockIdx.x;
  float m[4]; float ss = 0.f;
  #pragma unroll
  for (int j = 0; j < 4; ++j){
    int e = threadIdx.x + j*256;
    float s = 0.f;
    for (int n = 0; n < NTXT; ++n) s += F[((long long)(p*NTXT + n))*EMBED + e];
    s *= (1.0f/NTXT);
    m[j] = s; ss += s*s;
  }
  ss = wsum(ss);
  int wid = threadIdx.x >> 6, lane = threadIdx.x & 63;
  if (lane == 0) red[wid] = ss;
  __syncthreads();
  float inv = rsqrtf(red[0]+red[1]+red[2]+red[3]);
  #pragma unroll
  for (int j = 0; j < 4; ++j)
    OUT[p*EMBED + threadIdx.x + j*256] = m[j]*inv;
}

// ============================ launcher ============================

template<bool RF32>
static void run_all(const int* text, const float* cprompt, const float* tok_emb,
                    const float* pos_emb,
                    const ushort_t* Wqkv, const float* qkv_b,
                    const ushort_t* Wout, const float* out_b,
                    const float* ln1_w, const float* ln1_b,
                    const float* ln2_w, const float* ln2_b,
                    const ushort_t* Wfc, const float* fc_b,
                    const ushort_t* Wproj, const float* proj_b,
                    const float* lnf_w, const float* lnf_b, const float* tproj,
                    int* posy, void* H, ushort_t* Y, ushort_t* BIG,
                    ushort_t* FI, float* F, float* OUT, int sc, hipStream_t stream)
{
  const int rows_c = ROWS / sc;       // multiple of 128 for sc in {4,8}
  const int seqs_c = BSEQ / sc;

  k_posy<<<1, 128, 0, stream>>>(text, posy);
  k_embed<RF32><<<(ROWS*64)/256, 256, 0, stream>>>(text, cprompt, tok_emb, pos_emb, posy, H);

  for (int L = 0; L < LAYERS; ++L){
    k_ln<RF32><<<ROWS/4, 256, 0, stream>>>(H, ln1_w + L*WIDTH, ln1_b + L*WIDTH, Y, ROWS);
    for (int c = 0; c < sc; ++c){
      size_t r0 = (size_t)c * rows_c;
      k_gemm<0,RF32><<<dim3(12, rows_c/128), 256, 0, stream>>>(
          Y + r0*WIDTH, Wqkv + (size_t)L*1536*512, qkv_b + L*1536,
          nullptr, BIG, 512, 1536);
      k_attn<<<seqs_c*HEADS, 256, 0, stream>>>(BIG, Y + r0*WIDTH);
    }
    k_gemm<2,RF32><<<dim3(4, ROWS/128), 256, 0, stream>>>(
        Y, Wout + (size_t)L*512*512, out_b + L*512, H, nullptr, 512, 512);
    k_ln<RF32><<<ROWS/4, 256, 0, stream>>>(H, ln2_w + L*WIDTH, ln2_b + L*WIDTH, Y, ROWS);
    for (int c = 0; c < sc; ++c){
      size_t r0 = (size_t)c * rows_c;
      void* Hoff = RF32 ? (void*)((float*)H + r0*WIDTH) : (void*)((ushort_t*)H + r0*WIDTH);
      k_gemm<1,RF32><<<dim3(16, rows_c/128), 256, 0, stream>>>(
          Y + r0*WIDTH, Wfc + (size_t)L*2048*512, fc_b + L*2048,
          nullptr, BIG, 512, 2048);
      k_gemm<2,RF32><<<dim3(4, rows_c/128), 256, 0, stream>>>(
          BIG, Wproj + (size_t)L*512*2048, proj_b + L*512, Hoff, nullptr, 2048, 512);
    }
  }

  k_lnf_gather<RF32><<<BSEQ/4, 256, 0, stream>>>(H, posy, lnf_w, lnf_b, FI);
  k_fproj<<<(BSEQ*EMBED)/256, 256, 0, stream>>>(FI, tproj, F);
  k_rownorm<<<BSEQ, 256, 0, stream>>>(F);
  k_meannorm<<<PP, 256, 0, stream>>>(F, OUT);
}

extern "C" void kernel_launch(void* const* d_in, const int* in_sizes, int n_in,
                              void* d_out, int out_size, void* d_ws, size_t ws_size,
                              hipStream_t stream)
{
  const int*   text    = (const int*)d_in[0];
  const float* cprompt = (const float*)d_in[1];
  const float* tok_emb = (const float*)d_in[2];
  const float* pos_emb = (const float*)d_in[3];
  const float* qkv_w   = (const float*)d_in[4];
  const float* qkv_b   = (const float*)d_in[5];
  const float* out_w   = (const float*)d_in[6];
  const float* out_b   = (const float*)d_in[7];
  const float* ln1_w   = (const float*)d_in[8];
  const float* ln1_b   = (const float*)d_in[9];
  const float* ln2_w   = (const float*)d_in[10];
  const float* ln2_b   = (const float*)d_in[11];
  const float* fc_w    = (const float*)d_in[12];
  const float* fc_b    = (const float*)d_in[13];
  const float* proj_w  = (const float*)d_in[14];
  const float* proj_b  = (const float*)d_in[15];
  const float* lnf_w   = (const float*)d_in[16];
  const float* lnf_b   = (const float*)d_in[17];
  const float* tproj   = (const float*)d_in[18];

  const size_t nQKV = (size_t)LAYERS*1536*512;
  const size_t nOUT = (size_t)LAYERS*512*512;
  const size_t nFC  = (size_t)LAYERS*2048*512;
  const size_t nPRJ = (size_t)LAYERS*512*2048;
  const size_t nWB  = nQKV + nOUT + nFC + nPRJ;

  auto al = [](size_t b){ return (b + 255) & ~(size_t)255; };
  const size_t fixed = al(NTXT*sizeof(int)) + al((size_t)ROWS*WIDTH*2 /*Y*/)
                     + al((size_t)BSEQ*WIDTH*2 /*FI*/) + al((size_t)BSEQ*EMBED*4 /*F*/)
                     + al(nWB*2);
  // sc restricted to {4,8}: keeps BIG (<=80.7 MB) L3-resident between the
  // producing GEMM and consuming attn/proj launch (sc=1's 323 MB thrashes L3).
  int sc = 8; bool hf32 = false;
  const int scs[2] = {4, 8};
  bool found = false;
  for (int pass = 0; pass < 2 && !found; ++pass){
    size_t hbytes = (size_t)ROWS*WIDTH*(pass == 0 ? 4 : 2);
    for (int i = 0; i < 2; ++i){
      size_t big = (size_t)(ROWS/scs[i]) * 2048 * 2;
      if (fixed + al(hbytes) + al(big) <= ws_size){
        sc = scs[i]; hf32 = (pass == 0); found = true; break;
      }
    }
  }

  char* ws = (char*)d_ws;
  size_t off = 0;
  auto alloc = [&](size_t bytes)->char*{
    char* pp = ws + off; off += (bytes + 255) & ~(size_t)255; return pp;
  };
  int*      posy = (int*)     alloc(NTXT*sizeof(int));
  void*     H    = (void*)    alloc((size_t)ROWS*WIDTH*(hf32 ? 4 : 2));
  ushort_t* Y    = (ushort_t*)alloc((size_t)ROWS*WIDTH*2);
  ushort_t* BIG  = (ushort_t*)alloc((size_t)(ROWS/sc)*2048*2);
  ushort_t* FI   = (ushort_t*)alloc((size_t)BSEQ*WIDTH*2);
  float*    F    = (float*)   alloc((size_t)BSEQ*EMBED*4);
  ushort_t* WB   = (ushort_t*)alloc(nWB*2);
  ushort_t* Wqkv = WB;
  ushort_t* Wout = WB + nQKV;
  ushort_t* Wfc  = WB + nQKV + nOUT;
  ushort_t* Wprj = WB + nQKV + nOUT + nFC;

  k_conv<<<(int)((nQKV/4 + 255)/256), 256, 0, stream>>>(qkv_w,  Wqkv, (int)(nQKV/4));
  k_conv<<<(int)((nOUT/4 + 255)/256), 256, 0, stream>>>(out_w,  Wout, (int)(nOUT/4));
  k_conv<<<(int)((nFC /4 + 255)/256), 256, 0, stream>>>(fc_w,   Wfc,  (int)(nFC /4));
  k_conv<<<(int)((nPRJ/4 + 255)/256), 256, 0, stream>>>(proj_w, Wprj, (int)(nPRJ/4));

  if (hf32)
    run_all<true >(text, cprompt, tok_emb, pos_emb, Wqkv, qkv_b, Wout, out_b,
                   ln1_w, ln1_b, ln2_w, ln2_b, Wfc, fc_b, Wprj, proj_b,
                   lnf_w, lnf_b, tproj, posy, H, Y, BIG, FI, F,
                   (float*)d_out, sc, stream);
  else
    run_all<false>(text, cprompt, tok_emb, pos_emb, Wqkv, qkv_b, Wout, out_b,
                   ln1_w, ln1_b, ln2_w, ln2_b, Wfc, fc_b, Wprj, proj_b,
                   lnf_w, lnf_b, tproj, posy, H, Y, BIG, FI, F,
                   (float*)d_out, sc, stream);
}

// Round 4
// 14344.563 us; speedup vs baseline: 1.5574x; 1.0492x over previous
//
#include <hip/hip_runtime.h>
#include <math.h>
#include <stdint.h>

#define CTX 77
#define WIDTH 512
#define HEADS 8
#define DH 64
#define LAYERS 12
#define EMBED 1024
#define NTXT 128
#define PP 8
#define LPROMPT 16
#define EOTTOK 49407
#define BSEQ (PP*NTXT)          // 1024
#define ROWS (BSEQ*CTX)         // 78848

typedef unsigned short ushort_t;
typedef __attribute__((ext_vector_type(8))) short short8;
typedef __attribute__((ext_vector_type(4))) float floatx4;

__device__ __forceinline__ float b2f(ushort_t u){
  union { unsigned int i; float f; } x; x.i = ((unsigned int)u) << 16; return x.f;
}
__device__ __forceinline__ ushort_t f2b(float f){
  union { float f; unsigned int i; } x; x.f = f;
  unsigned int r = x.i + 0x7fffu + ((x.i >> 16) & 1u);
  return (ushort_t)(r >> 16);
}
__device__ __forceinline__ float wsum(float v){
  #pragma unroll
  for (int o = 32; o > 0; o >>= 1) v += __shfl_xor(v, o, 64);
  return v;
}
__device__ __forceinline__ float wmax(float v){
  #pragma unroll
  for (int o = 32; o > 0; o >>= 1) v = fmaxf(v, __shfl_xor(v, o, 64));
  return v;
}

// async global->LDS, 16 B per lane; LDS dest = wave-uniform base + lane*16.
__device__ __forceinline__ void async16(const void* g, void* l){
  __builtin_amdgcn_global_load_lds(
      (const __attribute__((address_space(1))) void*)(uintptr_t)g,
      (__attribute__((address_space(3))) void*)(uint32_t)(uintptr_t)l,
      16, 0, 0);
}

// -------- fp32 -> bf16 weight conversion (RNE), 4 elems/thread --------
__global__ __launch_bounds__(256) void k_conv(
    const float* __restrict__ s, ushort_t* __restrict__ d, int n4)
{
  int i = blockIdx.x * 256 + threadIdx.x;
  if (i < n4){
    float4 v = ((const float4*)s)[i];
    ushort_t o[4] = { f2b(v.x), f2b(v.y), f2b(v.z), f2b(v.w) };
    ((int2*)d)[i] = *(int2*)o;
  }
}

// -------- pos_y: first EOT position per text row --------
__global__ void k_posy(const int* __restrict__ text, int* __restrict__ posy){
  int n = threadIdx.x;
  if (n < NTXT){
    int p = 0;
    for (int t = 0; t < CTX; ++t){ if (text[n*CTX + t] == EOTTOK){ p = t; break; } }
    posy[n] = p;
  }
}

// -------- embedding + prompt splice + pos_emb -> H, 8 elems/thread --------
template<bool RF32>
__global__ __launch_bounds__(256) void k_embed(
    const int* __restrict__ text, const float* __restrict__ cprompt,
    const float* __restrict__ tok_emb, const float* __restrict__ pos_emb,
    const int* __restrict__ posy, void* __restrict__ Hp)
{
  long long idx = (long long)blockIdx.x * 256 + threadIdx.x;  // d8-chunk id
  int d8  = (int)(idx & 63) * 8;
  int row = (int)(idx >> 6);
  int t  = row % CTX;
  int pn = row / CTX;
  int n  = pn % NTXT;
  int p  = pn / NTXT;
  int py = posy[n];
  const float* src;
  if (t >= py && t < py + LPROMPT){
    src = cprompt + ((p*LPROMPT + (t - py))*WIDTH + d8);
  } else {
    int s0 = (t < py) ? t : (t - LPROMPT + 1);
    s0 = min(max(s0, 0), CTX-1);
    int tok = text[n*CTX + s0];
    src = tok_emb + ((long long)tok*WIDTH + d8);
  }
  const float* pe = pos_emb + (t*WIDTH + d8);
  float4 a0 = *(const float4*)(src);
  float4 a1 = *(const float4*)(src + 4);
  float4 b0 = *(const float4*)(pe);
  float4 b1 = *(const float4*)(pe + 4);
  float v[8] = { a0.x+b0.x, a0.y+b0.y, a0.z+b0.z, a0.w+b0.w,
                 a1.x+b1.x, a1.y+b1.y, a1.z+b1.z, a1.w+b1.w };
  long long base = (long long)row*WIDTH + d8;
  if constexpr (RF32){
    float4 o0 = {v[0],v[1],v[2],v[3]};
    float4 o1 = {v[4],v[5],v[6],v[7]};
    *(float4*)((float*)Hp + base)     = o0;
    *(float4*)((float*)Hp + base + 4) = o1;
  } else {
    ushort_t o[8];
    #pragma unroll
    for (int i = 0; i < 8; ++i) o[i] = f2b(v[i]);
    *(int4*)((ushort_t*)Hp + base) = *(int4*)o;
  }
}

// -------- LayerNorm: H -> Y(bf16), one wave per 512-row --------
template<bool RF32>
__global__ __launch_bounds__(256) void k_ln(
    const void* __restrict__ Hp, const float* __restrict__ w,
    const float* __restrict__ b, ushort_t* __restrict__ Y, int nrows)
{
  int wid = threadIdx.x >> 6, lane = threadIdx.x & 63;
  int row = blockIdx.x * 4 + wid;
  if (row >= nrows) return;
  float v[8];
  if constexpr (RF32){
    const float* x = (const float*)Hp + (long long)row * WIDTH;
    #pragma unroll
    for (int i = 0; i < 8; ++i) v[i] = x[lane*8 + i];
  } else {
    const ushort_t* x = (const ushort_t*)Hp + (long long)row * WIDTH;
    int4 raw = *(const int4*)(x + lane*8);
    ushort_t* u = (ushort_t*)&raw;
    #pragma unroll
    for (int i = 0; i < 8; ++i) v[i] = b2f(u[i]);
  }
  float s = 0.f, ss = 0.f;
  #pragma unroll
  for (int i = 0; i < 8; ++i){ s += v[i]; ss += v[i]*v[i]; }
  s = wsum(s); ss = wsum(ss);
  float mean = s * (1.0f/WIDTH);
  float var  = ss * (1.0f/WIDTH) - mean*mean;
  float rs = rsqrtf(var + 1e-5f);
  ushort_t o[8];
  #pragma unroll
  for (int i = 0; i < 8; ++i){
    int d = lane*8 + i;
    o[i] = f2b((v[i]-mean)*rs*w[d] + b[d]);
  }
  *(int4*)(Y + (long long)row*WIDTH + lane*8) = *(int4*)o;
}

// ============================================================================
// GEMM: C[M,N] = A[M,K](bf16) @ W[N,K]^T(bf16) + bias(fp32)
// 128x128 tile, BK=64, both-sides XOR swizzle (R1-verified), launch_bounds
// (256,4) pins 4 blocks/CU.  (unchanged from R2)
// MODE 0: O=bf16(acc+bias)  MODE 1: O=bf16(gelu(acc+bias))  MODE 2: H += acc+bias
// ============================================================================
template<int MODE, bool RF32>
__global__ __launch_bounds__(256, 4) void k_gemm(
    const ushort_t* __restrict__ A, const ushort_t* __restrict__ W,
    const float* __restrict__ bias, void* __restrict__ Hp,
    ushort_t* __restrict__ O, int K, int N)
{
  __shared__ ushort_t As[128*64];   // 16 KiB
  __shared__ ushort_t Bs[128*64];   // 16 KiB
  int tid  = threadIdx.x;
  int lane = tid & 63, wid = tid >> 6;
  int wm = wid >> 1, wn = wid & 1;
  long long m0 = (long long)blockIdx.y * 128;
  int n0 = blockIdx.x * 128;

  floatx4 acc[4][4];
  #pragma unroll
  for (int i = 0; i < 4; ++i)
    #pragma unroll
    for (int j = 0; j < 4; ++j){ floatx4 z = {0.f,0.f,0.f,0.f}; acc[i][j] = z; }

  const int srow = tid >> 3;                       // 0..31
  const int sc8  = ((tid ^ (tid >> 3)) & 7) * 8;   // pre-swizzled k-chunk
  const ushort_t* gA = A + (m0 + srow) * (long long)K + sc8;
  const ushort_t* gB = W + ((size_t)n0 + srow) * K + sc8;
  const size_t qstep = (size_t)32 * K;             // 32 rows
  const int lbase = wid * 512;                     // elems

  const int quad = lane >> 4, r = lane & 15;
  const int swz = (r & 7) * 8;                     // read-side XOR (elems)

  for (int k0 = 0; k0 < K; k0 += 64){
    __syncthreads();                 // prev iter's LDS reads done
    #pragma unroll
    for (int q = 0; q < 4; ++q){
      async16(gA + q*qstep, As + q*2048 + lbase);
      async16(gB + q*qstep, Bs + q*2048 + lbase);
    }
    gA += 64; gB += 64;
    __syncthreads();                 // staging drained (vmcnt0 before barrier)
    #pragma unroll
    for (int s = 0; s < 2; ++s){
      const int co = (s*32 + quad*8) ^ swz;
      short8 af[4], bf[4];
      #pragma unroll
      for (int i = 0; i < 4; ++i) af[i] = *(const short8*)(As + (wm*64 + i*16 + r)*64 + co);
      #pragma unroll
      for (int j = 0; j < 4; ++j) bf[j] = *(const short8*)(Bs + (wn*64 + j*16 + r)*64 + co);
      #pragma unroll
      for (int i = 0; i < 4; ++i)
        #pragma unroll
        for (int j = 0; j < 4; ++j)
          acc[i][j] = __builtin_amdgcn_mfma_f32_16x16x32_bf16(af[i], bf[j], acc[i][j], 0, 0, 0);
    }
  }

  int cn = lane & 15;
  #pragma unroll
  for (int i = 0; i < 4; ++i){
    #pragma unroll
    for (int j = 0; j < 4; ++j){
      int gcol = n0 + wn*64 + j*16 + cn;
      float bv = bias[gcol];
      #pragma unroll
      for (int rg = 0; rg < 4; ++rg){
        long long grow = m0 + wm*64 + i*16 + quad*4 + rg;
        float v = acc[i][j][rg] + bv;
        if (MODE == 0){
          O[grow*N + gcol] = f2b(v);
        } else if (MODE == 1){
          float g = v / (1.0f + __expf(-1.702f*v));
          O[grow*N + gcol] = f2b(g);
        } else {
          long long idx = grow*N + gcol;
          if constexpr (RF32) ((float*)Hp)[idx] += v;
          else { ushort_t* hb = (ushort_t*)Hp; hb[idx] = f2b(b2f(hb[idx]) + v); }
        }
      }
    }
  }
}

// ============================================================================
// MFMA causal attention: one block per (seq b, head h), 512 threads / 8 waves.
// LDS 41344 B (was 53056): 3 blocks/CU, 24 waves/CU (was 12).
//   Vt 64x104 bf16 @0      (13312)  written t-cols 0..95, read cols <=95
//   Qs 77x72  bf16 @13312  (11088)
//   Ks 77x72  bf16 @24400  (11088, ends 35488)
//   Ss tri f32     @13312  (12012; aliases Qs/Ks-head, written after QK)
//   Ps 77x104 bf16 @25328  (16016, ends 41344; aliases Ks tail, dead then)
// Ss is triangular-packed (causal: only kk<=q stored/read) — pure layout,
// arithmetic identical to R2.  MFMA row reads 77..79 stay in-bounds and are
// masked exactly as before (kk>q mask, store guards, arow clamp).
// ============================================================================
__global__ __launch_bounds__(512, 6) void k_attn(
    const ushort_t* __restrict__ QKV, ushort_t* __restrict__ Y)
{
  __shared__ char smem[41344];
  ushort_t* Vt = (ushort_t*)smem;                 // stride 104
  ushort_t* Qs = (ushort_t*)(smem + 13312);       // stride 72
  ushort_t* Ks = (ushort_t*)(smem + 24400);       // stride 72
  float*    Ss = (float*)(smem + 13312);          // triangular-packed
  ushort_t* Ps = (ushort_t*)(smem + 25328);       // stride 104

  int b = blockIdx.x >> 3, h = blockIdx.x & 7;
  int tid = threadIdx.x;
  int lane = tid & 63, wid = tid >> 6;            // wid 0..7
  int quad = lane >> 4, r = lane & 15;
  const ushort_t* base = QKV + (size_t)b*CTX*1536 + h*64;

  #pragma unroll
  for (int it = 0; it < 3; ++it){
    int id = tid + it*512;            // 0..1535 = 96 rows * 16 chunks
    int t  = id >> 4;
    int d4 = (id & 15) * 4;
    ushort_t q[4], k[4], v[4];
    if (t < CTX){
      const ushort_t* rp = base + (size_t)t*1536 + d4;
      *(int2*)q = *(const int2*)(rp);
      *(int2*)k = *(const int2*)(rp + 512);
      *(int2*)v = *(const int2*)(rp + 1024);
      *(int2*)(Qs + t*72 + d4) = *(int2*)q;
      *(int2*)(Ks + t*72 + d4) = *(int2*)k;
    } else {
      v[0]=v[1]=v[2]=v[3]=0;
    }
    #pragma unroll
    for (int i = 0; i < 4; ++i) Vt[(d4+i)*104 + t] = v[i];
  }
  __syncthreads();

  const int TI[15] = {0,1,1,2,2,2,3,3,3,3,4,4,4,4,4};
  const int TJ[15] = {0,0,1,0,1,2,0,1,2,3,0,1,2,3,4};
  floatx4 cS[2];
  int ntile = 0;
  for (int tt = wid; tt < 15; tt += 8, ++ntile){
    int i = TI[tt], j = TJ[tt];
    floatx4 c = {0.f,0.f,0.f,0.f};
    #pragma unroll
    for (int s = 0; s < 2; ++s){
      short8 aq = *(const short8*)(Qs + (i*16 + r)*72 + s*32 + quad*8);
      short8 bk = *(const short8*)(Ks + (j*16 + r)*72 + s*32 + quad*8);
      c = __builtin_amdgcn_mfma_f32_16x16x32_bf16(aq, bk, c, 0, 0, 0);
    }
    cS[ntile] = c;
  }
  __syncthreads();

  {
    int idx = 0;
    for (int tt = wid; tt < 15; tt += 8, ++idx){
      int i = TI[tt], j = TJ[tt];
      #pragma unroll
      for (int rg = 0; rg < 4; ++rg){
        int q  = i*16 + quad*4 + rg;
        int kk = j*16 + r;
        if (q < CTX && kk <= q)
          Ss[((q*(q+1)) >> 1) + kk] = cS[idx][rg] * 0.125f;
      }
    }
  }
  __syncthreads();

  for (int q = wid; q < CTX; q += 8){
    int triq = (q*(q+1)) >> 1;
    int k1 = 64 + lane;
    float s0 = (lane <= q) ? Ss[triq + lane] : -1e30f;
    float s1 = (k1  <= q) ? Ss[triq + k1 ]  : -1e30f;
    float mx = wmax(fmaxf(s0, s1));
    float e0 = (lane <= q) ? __expf(s0 - mx) : 0.0f;
    float e1 = (k1  <= q) ? __expf(s1 - mx) : 0.0f;
    float inv = 1.0f / wsum(e0 + e1);
    Ps[q*104 + lane] = f2b(e0 * inv);
    if (lane < 32) Ps[q*104 + 64 + lane] = f2b(e1 * inv);
  }
  __syncthreads();

  for (int tt = wid; tt < 20; tt += 8){
    int mi = tt >> 2, ni = tt & 3;
    int arow = min(mi*16 + r, CTX-1);     // clamp garbage rows 77..79
    floatx4 c = {0.f,0.f,0.f,0.f};
    #pragma unroll
    for (int kc = 0; kc < 3; ++kc){
      short8 ap = *(const short8*)(Ps + arow*104 + kc*32 + quad*8);
      short8 bv = *(const short8*)(Vt + (ni*16 + r)*104 + kc*32 + quad*8);
      c = __builtin_amdgcn_mfma_f32_16x16x32_bf16(ap, bv, c, 0, 0, 0);
    }
    #pragma unroll
    for (int rg = 0; rg < 4; ++rg){
      int q = mi*16 + quad*4 + rg;
      if (q < CTX)
        Y[((size_t)b*CTX + q)*WIDTH + h*64 + ni*16 + r] = f2b(c[rg]);
    }
  }
}

// -------- gather EOT+LP-1 rows, final LN -> FI (bf16 [1024,512]) --------
template<bool RF32>
__global__ __launch_bounds__(256) void k_lnf_gather(
    const void* __restrict__ Hp, const int* __restrict__ posy,
    const float* __restrict__ w, const float* __restrict__ b,
    ushort_t* __restrict__ FI)
{
  int wid = threadIdx.x >> 6, lane = threadIdx.x & 63;
  int rr = blockIdx.x * 4 + wid;
  if (rr >= BSEQ) return;
  int n = rr % NTXT;
  int tok = posy[n] + LPROMPT - 1;
  long long row = (long long)rr*CTX + tok;
  float v[8];
  if constexpr (RF32){
    const float* x = (const float*)Hp + row * WIDTH;
    #pragma unroll
    for (int i = 0; i < 8; ++i) v[i] = x[lane*8 + i];
  } else {
    const ushort_t* x = (const ushort_t*)Hp + row * WIDTH;
    int4 raw = *(const int4*)(x + lane*8);
    ushort_t* u = (ushort_t*)&raw;
    #pragma unroll
    for (int i = 0; i < 8; ++i) v[i] = b2f(u[i]);
  }
  float s = 0.f, ss = 0.f;
  #pragma unroll
  for (int i = 0; i < 8; ++i){ s += v[i]; ss += v[i]*v[i]; }
  s = wsum(s); ss = wsum(ss);
  float mean = s * (1.0f/WIDTH);
  float var  = ss * (1.0f/WIDTH) - mean*mean;
  float rs = rsqrtf(var + 1e-5f);
  ushort_t o[8];
  #pragma unroll
  for (int i = 0; i < 8; ++i){
    int d = lane*8 + i;
    o[i] = f2b((v[i]-mean)*rs*w[d] + b[d]);
  }
  *(int4*)(FI + (long long)rr*WIDTH + lane*8) = *(int4*)o;
}

// -------- final projection: F[1024,1024] = FI[1024,512](bf16) @ TP[512,1024](fp32) --------
__global__ __launch_bounds__(256) void k_fproj(
    const ushort_t* __restrict__ FI, const float* __restrict__ TP,
    float* __restrict__ F)
{
  int idx = blockIdx.x * 256 + threadIdx.x;
  int e = idx & (EMBED-1);
  int m = idx >> 10;
  float acc = 0.f;
  #pragma unroll 8
  for (int k = 0; k < WIDTH; ++k)
    acc += b2f(FI[m*WIDTH + k]) * TP[k*EMBED + e];
  F[idx] = acc;
}

// -------- per-row L2 normalize in place --------
__global__ __launch_bounds__(256) void k_rownorm(float* __restrict__ F)
{
  __shared__ float red[4];
  int rr = blockIdx.x;
  float* x = F + (long long)rr*EMBED;
  float ss = 0.f;
  for (int i = threadIdx.x; i < EMBED; i += 256){ float v = x[i]; ss += v*v; }
  ss = wsum(ss);
  int wid = threadIdx.x >> 6, lane = threadIdx.x & 63;
  if (lane == 0) red[wid] = ss;
  __syncthreads();
  float inv = rsqrtf(red[0]+red[1]+red[2]+red[3]);
  for (int i = threadIdx.x; i < EMBED; i += 256) x[i] *= inv;
}

// -------- mean over n, normalize, write fp32 out --------
__global__ __launch_bounds__(256) void k_meannorm(
    const float* __restrict__ F, float* __restrict__ OUT)
{
  __shared__ float red[4];
  int p = blockIdx.x;
  float m[4]; float ss = 0.f;
  #pragma unroll
  for (int j = 0; j < 4; ++j){
    int e = threadIdx.x + j*256;
    float s = 0.f;
    for (int n = 0; n < NTXT; ++n) s += F[((long long)(p*NTXT + n))*EMBED + e];
    s *= (1.0f/NTXT);
    m[j] = s; ss += s*s;
  }
  ss = wsum(ss);
  int wid = threadIdx.x >> 6, lane = threadIdx.x & 63;
  if (lane == 0) red[wid] = ss;
  __syncthreads();
  float inv = rsqrtf(red[0]+red[1]+red[2]+red[3]);
  #pragma unroll
  for (int j = 0; j < 4; ++j)
    OUT[p*EMBED + threadIdx.x + j*256] = m[j]*inv;
}

// ============================ launcher ============================

template<bool RF32>
static void run_all(const int* text, const float* cprompt, const float* tok_emb,
                    const float* pos_emb,
                    const ushort_t* Wqkv, const float* qkv_b,
                    const ushort_t* Wout, const float* out_b,
                    const float* ln1_w, const float* ln1_b,
                    const float* ln2_w, const float* ln2_b,
                    const ushort_t* Wfc, const float* fc_b,
                    const ushort_t* Wproj, const float* proj_b,
                    const float* lnf_w, const float* lnf_b, const float* tproj,
                    int* posy, void* H, ushort_t* Y, ushort_t* BIG,
                    ushort_t* FI, float* F, float* OUT, int sc, hipStream_t stream)
{
  const int rows_c = ROWS / sc;       // multiple of 128 for sc in {4,8}
  const int seqs_c = BSEQ / sc;

  k_posy<<<1, 128, 0, stream>>>(text, posy);
  k_embed<RF32><<<(ROWS*64)/256, 256, 0, stream>>>(text, cprompt, tok_emb, pos_emb, posy, H);

  for (int L = 0; L < LAYERS; ++L){
    k_ln<RF32><<<ROWS/4, 256, 0, stream>>>(H, ln1_w + L*WIDTH, ln1_b + L*WIDTH, Y, ROWS);
    for (int c = 0; c < sc; ++c){
      size_t r0 = (size_t)c * rows_c;
      k_gemm<0,RF32><<<dim3(12, rows_c/128), 256, 0, stream>>>(
          Y + r0*WIDTH, Wqkv + (size_t)L*1536*512, qkv_b + L*1536,
          nullptr, BIG, 512, 1536);
      k_attn<<<seqs_c*HEADS, 512, 0, stream>>>(BIG, Y + r0*WIDTH);
    }
    k_gemm<2,RF32><<<dim3(4, ROWS/128), 256, 0, stream>>>(
        Y, Wout + (size_t)L*512*512, out_b + L*512, H, nullptr, 512, 512);
    k_ln<RF32><<<ROWS/4, 256, 0, stream>>>(H, ln2_w + L*WIDTH, ln2_b + L*WIDTH, Y, ROWS);
    for (int c = 0; c < sc; ++c){
      size_t r0 = (size_t)c * rows_c;
      void* Hoff = RF32 ? (void*)((float*)H + r0*WIDTH) : (void*)((ushort_t*)H + r0*WIDTH);
      k_gemm<1,RF32><<<dim3(16, rows_c/128), 256, 0, stream>>>(
          Y + r0*WIDTH, Wfc + (size_t)L*2048*512, fc_b + L*2048,
          nullptr, BIG, 512, 2048);
      k_gemm<2,RF32><<<dim3(4, rows_c/128), 256, 0, stream>>>(
          BIG, Wproj + (size_t)L*512*2048, proj_b + L*512, Hoff, nullptr, 2048, 512);
    }
  }

  k_lnf_gather<RF32><<<BSEQ/4, 256, 0, stream>>>(H, posy, lnf_w, lnf_b, FI);
  k_fproj<<<(BSEQ*EMBED)/256, 256, 0, stream>>>(FI, tproj, F);
  k_rownorm<<<BSEQ, 256, 0, stream>>>(F);
  k_meannorm<<<PP, 256, 0, stream>>>(F, OUT);
}

extern "C" void kernel_launch(void* const* d_in, const int* in_sizes, int n_in,
                              void* d_out, int out_size, void* d_ws, size_t ws_size,
                              hipStream_t stream)
{
  const int*   text    = (const int*)d_in[0];
  const float* cprompt = (const float*)d_in[1];
  const float* tok_emb = (const float*)d_in[2];
  const float* pos_emb = (const float*)d_in[3];
  const float* qkv_w   = (const float*)d_in[4];
  const float* qkv_b   = (const float*)d_in[5];
  const float* out_w   = (const float*)d_in[6];
  const float* out_b   = (const float*)d_in[7];
  const float* ln1_w   = (const float*)d_in[8];
  const float* ln1_b   = (const float*)d_in[9];
  const float* ln2_w   = (const float*)d_in[10];
  const float* ln2_b   = (const float*)d_in[11];
  const float* fc_w    = (const float*)d_in[12];
  const float* fc_b    = (const float*)d_in[13];
  const float* proj_w  = (const float*)d_in[14];
  const float* proj_b  = (const float*)d_in[15];
  const float* lnf_w   = (const float*)d_in[16];
  const float* lnf_b   = (const float*)d_in[17];
  const float* tproj   = (const float*)d_in[18];

  const size_t nQKV = (size_t)LAYERS*1536*512;
  const size_t nOUT = (size_t)LAYERS*512*512;
  const size_t nFC  = (size_t)LAYERS*2048*512;
  const size_t nPRJ = (size_t)LAYERS*512*2048;
  const size_t nWB  = nQKV + nOUT + nFC + nPRJ;

  auto al = [](size_t b){ return (b + 255) & ~(size_t)255; };
  const size_t fixed = al(NTXT*sizeof(int)) + al((size_t)ROWS*WIDTH*2 /*Y*/)
                     + al((size_t)BSEQ*WIDTH*2 /*FI*/) + al((size_t)BSEQ*EMBED*4 /*F*/)
                     + al(nWB*2);
  // sc restricted to {4,8}: keeps BIG (<=80.7 MB) L3-resident between the
  // producing GEMM and consuming attn/proj launch (sc=1's 323 MB thrashes L3).
  int sc = 8; bool hf32 = false;
  const int scs[2] = {4, 8};
  bool found = false;
  for (int pass = 0; pass < 2 && !found; ++pass){
    size_t hbytes = (size_t)ROWS*WIDTH*(pass == 0 ? 4 : 2);
    for (int i = 0; i < 2; ++i){
      size_t big = (size_t)(ROWS/scs[i]) * 2048 * 2;
      if (fixed + al(hbytes) + al(big) <= ws_size){
        sc = scs[i]; hf32 = (pass == 0); found = true; break;
      }
    }
  }

  char* ws = (char*)d_ws;
  size_t off = 0;
  auto alloc = [&](size_t bytes)->char*{
    char* pp = ws + off; off += (bytes + 255) & ~(size_t)255; return pp;
  };
  int*      posy = (int*)     alloc(NTXT*sizeof(int));
  void*     H    = (void*)    alloc((size_t)ROWS*WIDTH*(hf32 ? 4 : 2));
  ushort_t* Y    = (ushort_t*)alloc((size_t)ROWS*WIDTH*2);
  ushort_t* BIG  = (ushort_t*)alloc((size_t)(ROWS/sc)*2048*2);
  ushort_t* FI   = (ushort_t*)alloc((size_t)BSEQ*WIDTH*2);
  float*    F    = (float*)   alloc((size_t)BSEQ*EMBED*4);
  ushort_t* WB   = (ushort_t*)alloc(nWB*2);
  ushort_t* Wqkv = WB;
  ushort_t* Wout = WB + nQKV;
  ushort_t* Wfc  = WB + nQKV + nOUT;
  ushort_t* Wprj = WB + nQKV + nOUT + nFC;

  k_conv<<<(int)((nQKV/4 + 255)/256), 256, 0, stream>>>(qkv_w,  Wqkv, (int)(nQKV/4));
  k_conv<<<(int)((nOUT/4 + 255)/256), 256, 0, stream>>>(out_w,  Wout, (int)(nOUT/4));
  k_conv<<<(int)((nFC /4 + 255)/256), 256, 0, stream>>>(fc_w,   Wfc,  (int)(nFC /4));
  k_conv<<<(int)((nPRJ/4 + 255)/256), 256, 0, stream>>>(proj_w, Wprj, (int)(nPRJ/4));

  if (hf32)
    run_all<true >(text, cprompt, tok_emb, pos_emb, Wqkv, qkv_b, Wout, out_b,
                   ln1_w, ln1_b, ln2_w, ln2_b, Wfc, fc_b, Wprj, proj_b,
                   lnf_w, lnf_b, tproj, posy, H, Y, BIG, FI, F,
                   (float*)d_out, sc, stream);
  else
    run_all<false>(text, cprompt, tok_emb, pos_emb, Wqkv, qkv_b, Wout, out_b,
                   ln1_w, ln1_b, ln2_w, ln2_b, Wfc, fc_b, Wprj, proj_b,
                   lnf_w, lnf_b, tproj, posy, H, Y, BIG, FI, F,
                   (float*)d_out, sc, stream);
}